// Round 1
// baseline (35971.555 us; speedup 1.0000x reference)
//
#include <hip/hip_runtime.h>
#include <math.h>

// ---------------------------------------------------------------------------
// Workspace layout (float element offsets). Peak need ~196 MB.
// ---------------------------------------------------------------------------
static const size_t OFF_META   = 0;                      // 256 ints (as bytes at ws start)
static const size_t OFF_SIMS   = 256;                    // (6,6,48,48) = 82944
static const size_t ARENA      = 83200;
static const size_t OFF_B1     = ARENA;                  // (2,64,192,192)  = 4718592
static const size_t OFF_B2     = OFF_B1 + 4718592;       // (2,256,96,96)   = 4718592
static const size_t OFF_F3     = OFF_B2 + 4718592;       // (2,512,48,48)   = 2359296
static const size_t OFF_F4     = OFF_F3 + 2359296;       // (2,1024,24,24)  = 1179648
static const size_t OFF_PRAW   = OFF_F4 + 1179648;       // 2359296
static const size_t OFF_PSC    = OFF_PRAW + 2359296;     // 8957952
static const size_t OFF_SIMRAW = OFF_PSC + 8957952;      // 51840
// regressor phase reuses the arena (backbone/feature buffers dead by then)
static const size_t OFF_R1     = ARENA;                  // (6,196,48,48)   = 2709504
static const size_t OFF_U1     = OFF_R1 + 2709504;       // (6,196,96,96)   = 10838016
static const size_t OFF_R2     = OFF_U1 + 10838016;      // (6,128,96,96)   = 7077888
static const size_t OFF_U2     = OFF_R2 + 7077888;       // (6,128,192,192) = 28311552
static const size_t OFF_R3     = ARENA;                  // (6,64,192,192)  = 14155776 (over dead R1/U1/R2-head)

// ---------------------------------------------------------------------------
// meta: per (b,lvl) m=b*2+lvl, base=m*32 ints:
//  [p*4+0..3] = top,left,bot,right ; [12]=PH [13]=PW ; [14+2s]=PHs [15+2s]=PWs
// ---------------------------------------------------------------------------
__global__ __launch_bounds__(64) void k_meta(const float* __restrict__ tlbrs,
                                             int* __restrict__ meta)
{
    if (threadIdx.x != 0 || blockIdx.x != 0) return;
    const double SC[3] = {1.0, 0.9, 1.1};
    for (int b = 0; b < 2; ++b)
        for (int lvl = 0; lvl < 2; ++lvl) {
            int FH = lvl ? 24 : 48;
            float scaling = lvl ? 16.f : 8.f;
            int base = (b * 2 + lvl) * 32;
            int PH = 0, PW = 0;
            for (int p = 0; p < 3; ++p) {
                const float* t4 = tlbrs + (b * 3 + p) * 4;
                float st = t4[0] / scaling, sl = t4[1] / scaling;
                float sb = t4[2] / scaling, sr = t4[3] / scaling;
                int top  = (int)fmaxf(floorf(st), 0.f);
                int left = (int)fmaxf(floorf(sl), 0.f);
                int bot  = (int)fminf(ceilf(sb) + 1.f, (float)FH);
                int rgt  = (int)fminf(ceilf(sr) + 1.f, (float)FH);
                meta[base + p * 4 + 0] = top;
                meta[base + p * 4 + 1] = left;
                meta[base + p * 4 + 2] = bot;
                meta[base + p * 4 + 3] = rgt;
                PH = max(PH, bot - top);
                PW = max(PW, rgt - left);
            }
            meta[base + 12] = PH;
            meta[base + 13] = PW;
            for (int s = 0; s < 3; ++s) {
                int PHs = (int)ceil((double)PH * SC[s]);   // fp64, bit-match numpy
                int PWs = (int)ceil((double)PW * SC[s]);
                if (PHs < 1) PHs = PH;
                if (PWs < 1) PWs = PW;
                meta[base + 14 + s * 2] = PHs;
                meta[base + 15 + s * 2] = PWs;
            }
        }
}

// ---------------------------------------------------------------------------
// Generic direct conv (stride s, zero pad, always relu, optional bias).
// 16x16 output tile per block, z = n*Cout+co, weights for co staged in LDS.
// ---------------------------------------------------------------------------
__global__ __launch_bounds__(256) void k_conv(const float* __restrict__ in,
    const float* __restrict__ w, const float* __restrict__ bias,
    float* __restrict__ out, int N, int Cin, int Hin, int Win,
    int Cout, int Hout, int Wout, int KH, int KW, int stride, int padT, int padL)
{
    extern __shared__ float wsm[];
    int co = blockIdx.z % Cout, n = blockIdx.z / Cout;
    int wcount = Cin * KH * KW;
    int tid = threadIdx.y * 16 + threadIdx.x;
    for (int i = tid; i < wcount; i += 256) wsm[i] = w[(size_t)co * wcount + i];
    __syncthreads();
    int x = blockIdx.x * 16 + threadIdx.x;
    int y = blockIdx.y * 16 + threadIdx.y;
    if (x >= Wout || y >= Hout) return;
    float acc = bias ? bias[co] : 0.f;
    const float* inb = in + (size_t)n * Cin * Hin * Win;
    for (int ci = 0; ci < Cin; ++ci) {
        const float* ip = inb + (size_t)ci * Hin * Win;
        const float* wp = wsm + ci * KH * KW;
        for (int ky = 0; ky < KH; ++ky) {
            int iy = y * stride - padT + ky;
            if ((unsigned)iy >= (unsigned)Hin) continue;
            const float* row = ip + (size_t)iy * Win;
            const float* wrow = wp + ky * KW;
            for (int kx = 0; kx < KW; ++kx) {
                int ix = x * stride - padL + kx;
                if ((unsigned)ix < (unsigned)Win)
                    acc = fmaf(row[ix], wrow[kx], acc);
            }
        }
    }
    acc = fmaxf(acc, 0.f);
    out[(((size_t)n * Cout + co) * Hout + y) * Wout + x] = acc;
}

// ---------------------------------------------------------------------------
// Patch crop + half-pixel bilinear resize to (PH,PW); stride-16 planes.
// grid: z = (b*2+lvl)*3+p (12), y = c (1024, masked), block 256 = 16x16
// ---------------------------------------------------------------------------
__global__ __launch_bounds__(256) void k_praw(const float* __restrict__ f3,
    const float* __restrict__ f4, const int* __restrict__ meta,
    float* __restrict__ praw)
{
    int z = blockIdx.z;
    int p = z % 3, m = z / 3, lvl = m % 2, b = m / 2;
    int c = blockIdx.y;
    int FC = lvl ? 1024 : 512;
    if (c >= FC) return;
    int FH = lvl ? 24 : 48;
    const int* mb = meta + m * 32;
    int PH = mb[12], PW = mb[13];
    int oy = threadIdx.x / 16, ox = threadIdx.x % 16;
    if (oy >= PH || ox >= PW) return;
    int top = mb[p * 4 + 0], left = mb[p * 4 + 1];
    int bot = mb[p * 4 + 2], rgt = mb[p * 4 + 3];
    int h = bot - top, w = rgt - left;
    const float* fm = lvl ? (f4 + ((size_t)b * 1024 + c) * 576)
                          : (f3 + ((size_t)b * 512 + c) * 2304);
    float sy = ((oy + 0.5f) * h) / PH - 0.5f;
    sy = fminf(fmaxf(sy, 0.f), (float)(h - 1));
    int y0 = (int)floorf(sy); float ty = sy - y0; int y1 = min(y0 + 1, h - 1);
    float sx = ((ox + 0.5f) * w) / PW - 0.5f;
    sx = fminf(fmaxf(sx, 0.f), (float)(w - 1));
    int x0 = (int)floorf(sx); float tx = sx - x0; int x1 = min(x0 + 1, w - 1);
    const float* r0 = fm + (size_t)(top + y0) * FH;
    const float* r1 = fm + (size_t)(top + y1) * FH;
    float v = (1.f - ty) * ((1.f - tx) * r0[left + x0] + tx * r0[left + x1])
            +        ty  * ((1.f - tx) * r1[left + x0] + tx * r1[left + x1]);
    size_t base = (size_t)(b * 1179648 + (lvl ? 393216 : 0)) + ((size_t)p * FC + c) * 256;
    praw[base + oy * 16 + ox] = v;
}

// ---------------------------------------------------------------------------
// Scale-resize patches to (PHs,PWs); stride-18 planes.
// grid: z = b*18+lvl*9+s*3+p (36), y = c, x = 2 blocks x 256 over 18x18
// ---------------------------------------------------------------------------
__global__ __launch_bounds__(256) void k_psc(const float* __restrict__ praw,
    const int* __restrict__ meta, float* __restrict__ psc)
{
    int z = blockIdx.z;
    int p = z % 3, s = (z / 3) % 3, lvl = (z / 9) % 2, b = z / 18;
    int c = blockIdx.y;
    int FC = lvl ? 1024 : 512;
    if (c >= FC) return;
    const int* mb = meta + (b * 2 + lvl) * 32;
    int PH = mb[12], PW = mb[13];
    int PHs = mb[14 + s * 2], PWs = mb[15 + s * 2];
    int idx = blockIdx.x * 256 + threadIdx.x;
    int ys = idx / 18, xs = idx % 18;
    if (ys >= PHs || xs >= PWs) return;
    const float* src = praw + (size_t)(b * 1179648 + (lvl ? 393216 : 0))
                            + ((size_t)p * FC + c) * 256;
    float sy = ((ys + 0.5f) * PH) / PHs - 0.5f;
    sy = fminf(fmaxf(sy, 0.f), (float)(PH - 1));
    int y0 = (int)floorf(sy); float ty = sy - y0; int y1 = min(y0 + 1, PH - 1);
    float sx = ((xs + 0.5f) * PW) / PWs - 0.5f;
    sx = fminf(fmaxf(sx, 0.f), (float)(PW - 1));
    int x0 = (int)floorf(sx); float tx = sx - x0; int x1 = min(x0 + 1, PW - 1);
    float v = (1.f - ty) * ((1.f - tx) * src[y0 * 16 + x0] + tx * src[y0 * 16 + x1])
            +        ty  * ((1.f - tx) * src[y1 * 16 + x0] + tx * src[y1 * 16 + x1]);
    size_t base = (size_t)b * 4478976 + (lvl ? (1492992 + (size_t)s * 995328)
                                             : ((size_t)s * 497664));
    psc[base + ((size_t)p * FC + c) * 324 + ys * 18 + xs] = v;
}

__global__ __launch_bounds__(256) void k_fill0(float* p, int n)
{
    int i = blockIdx.x * 256 + threadIdx.x;
    if (i < n) p[i] = 0.f;
}

// ---------------------------------------------------------------------------
// Similarity conv: sim[p,y,x] += sum_{c in group} fm[c,..] * psc[p,c,..]
// grid: z = b*18+lvl*9+s*3+p (36), y = c-group (64ch each), x covers pixels
// ---------------------------------------------------------------------------
__global__ __launch_bounds__(256) void k_simconv(const float* __restrict__ f3,
    const float* __restrict__ f4, const float* __restrict__ psc,
    const int* __restrict__ meta, float* __restrict__ simraw)
{
    int z = blockIdx.z;
    int p = z % 3, s = (z / 3) % 3, lvl = (z / 9) % 2, b = z / 18;
    int FC = lvl ? 1024 : 512, FH = lvl ? 24 : 48;
    int FHFW = FH * FH;
    int cg = blockIdx.y;
    if (cg >= FC / 64) return;
    int pix = blockIdx.x * 256 + threadIdx.x;
    if (pix >= FHFW) return;
    int y = pix / FH, x = pix % FH;
    const int* mb = meta + (b * 2 + lvl) * 32;
    int PHs = mb[14 + s * 2], PWs = mb[15 + s * 2];
    int padT = PHs >> 1, padL = PWs >> 1;
    const float* fmb = lvl ? (f4 + (size_t)b * 1024 * 576)
                           : (f3 + (size_t)b * 512 * 2304);
    size_t pbase = (size_t)b * 4478976 + (lvl ? (1492992 + (size_t)s * 995328)
                                              : ((size_t)s * 497664));
    const float* wb = psc + pbase + (size_t)p * FC * 324;
    float acc = 0.f;
    for (int cc = 0; cc < 64; ++cc) {
        int c = cg * 64 + cc;
        const float* fm = fmb + (size_t)c * FHFW;
        const float* wc = wb + (size_t)c * 324;
        for (int ky = 0; ky < PHs; ++ky) {
            int iy = y - padT + ky;
            if ((unsigned)iy >= (unsigned)FH) continue;
            const float* row = fm + iy * FH;
            const float* wrow = wc + ky * 18;
            for (int kx = 0; kx < PWs; ++kx) {
                int ix = x - padL + kx;
                if ((unsigned)ix < (unsigned)FH)
                    acc = fmaf(row[ix], wrow[kx], acc);
            }
        }
    }
    size_t sb = (size_t)b * 25920 + (lvl ? (20736 + (size_t)s * 1728)
                                         : ((size_t)s * 6912));
    atomicAdd(&simraw[sb + (size_t)p * FHFW + pix], acc);
}

// ---------------------------------------------------------------------------
// Assemble sims (n=b*3+p, scat=lvl*3+s, 48x48); f4 level upscaled 24->48.
// ---------------------------------------------------------------------------
__global__ __launch_bounds__(256) void k_sims(const float* __restrict__ simraw,
    float* __restrict__ sims)
{
    int idx = blockIdx.x * 256 + threadIdx.x;
    if (idx >= 82944) return;
    int x = idx % 48, y = (idx / 48) % 48;
    int scat = (idx / 2304) % 6, p = (idx / 13824) % 3, b = idx / 41472;
    int lvl = scat / 3, s = scat % 3;
    float v;
    if (lvl == 0) {
        v = simraw[(size_t)b * 25920 + (size_t)s * 6912 + (size_t)p * 2304 + y * 48 + x];
    } else {
        const float* src = simraw + (size_t)b * 25920 + 20736 + (size_t)s * 1728
                                  + (size_t)p * 576;
        float sy = (y + 0.5f) * 0.5f - 0.5f; sy = fminf(fmaxf(sy, 0.f), 23.f);
        int y0 = (int)floorf(sy); float ty = sy - y0; int y1 = min(y0 + 1, 23);
        float sx = (x + 0.5f) * 0.5f - 0.5f; sx = fminf(fmaxf(sx, 0.f), 23.f);
        int x0 = (int)floorf(sx); float tx = sx - x0; int x1 = min(x0 + 1, 23);
        v = (1.f - ty) * ((1.f - tx) * src[y0 * 24 + x0] + tx * src[y0 * 24 + x1])
          +        ty  * ((1.f - tx) * src[y1 * 24 + x0] + tx * src[y1 * 24 + x1]);
    }
    sims[((size_t)(b * 3 + p) * 6 + scat) * 2304 + y * 48 + x] = v;
}

// ---------------------------------------------------------------------------
// align-corners 2x bilinear upsample (exact rational index math)
// ---------------------------------------------------------------------------
__global__ __launch_bounds__(256) void k_up2ac(const float* __restrict__ in,
    float* __restrict__ out, int NC, int Hin, int Win)
{
    int Hout = 2 * Hin, Wout = 2 * Win;
    size_t total = (size_t)NC * Hout * Wout;
    size_t idx = (size_t)blockIdx.x * 256 + threadIdx.x;
    if (idx >= total) return;
    int x = (int)(idx % Wout);
    int y = (int)((idx / Wout) % Hout);
    int nc = (int)(idx / ((size_t)Wout * Hout));
    int dh = 2 * Hin - 1, dw = 2 * Win - 1;
    int ay = y * (Hin - 1);
    int y0 = ay / dh; int y1 = min(y0 + 1, Hin - 1);
    float ty = (float)(ay - y0 * dh) / (float)dh;
    int ax = x * (Win - 1);
    int x0 = ax / dw; int x1 = min(x0 + 1, Win - 1);
    float tx = (float)(ax - x0 * dw) / (float)dw;
    const float* p = in + (size_t)nc * Hin * Win;
    float v00 = p[(size_t)y0 * Win + x0], v01 = p[(size_t)y0 * Win + x1];
    float v10 = p[(size_t)y1 * Win + x0], v11 = p[(size_t)y1 * Win + x1];
    out[idx] = (1.f - ty) * ((1.f - tx) * v00 + tx * v01)
             +        ty  * ((1.f - tx) * v10 + tx * v11);
}

// ---------------------------------------------------------------------------
// Fused: upsample2x_ac(r3) -> conv1x1(rw4)+relu -> conv1x1(rw5)+relu -> max_p
// One thread per output pixel (b,y,x). Avoids 340 MB of u3/r4.
// ---------------------------------------------------------------------------
__global__ __launch_bounds__(256) void k_final(const float* __restrict__ r3,
    const float* __restrict__ w4, const float* __restrict__ b4,
    const float* __restrict__ w5, const float* __restrict__ b5,
    float* __restrict__ out)
{
    __shared__ float sw4[2048];
    __shared__ float sb4[32];
    __shared__ float sw5[32];
    int tid = threadIdx.x;
    for (int i = tid; i < 2048; i += 256) sw4[i] = w4[i];
    if (tid < 32) { sb4[tid] = b4[tid]; sw5[tid] = w5[tid]; }
    __syncthreads();
    int idx = blockIdx.x * 256 + tid;          // 0..294911
    int x = idx % 384, y = (idx / 384) % 384, b = idx / 147456;
    // 192 -> 384 align-corners coords
    int ay = y * 191; int y0 = ay / 383; int y1 = min(y0 + 1, 191);
    float ty = (float)(ay - y0 * 383) / 383.f;
    int ax = x * 191; int x0 = ax / 383; int x1 = min(x0 + 1, 191);
    float tx = (float)(ax - x0 * 383) / 383.f;
    float w00 = (1.f - ty) * (1.f - tx), w01 = (1.f - ty) * tx;
    float w10 = ty * (1.f - tx), w11 = ty * tx;
    float best = 0.f;   // all candidates are relu outputs (>= 0)
    for (int p = 0; p < 3; ++p) {
        int n = b * 3 + p;
        float acc[32];
#pragma unroll
        for (int co = 0; co < 32; ++co) acc[co] = sb4[co];
        const float* rb = r3 + (size_t)n * 64 * 192 * 192;
        for (int ci = 0; ci < 64; ++ci) {
            const float* pl = rb + (size_t)ci * 192 * 192;
            float v = w00 * pl[y0 * 192 + x0] + w01 * pl[y0 * 192 + x1]
                    + w10 * pl[y1 * 192 + x0] + w11 * pl[y1 * 192 + x1];
#pragma unroll
            for (int co = 0; co < 32; ++co)
                acc[co] = fmaf(sw4[co * 64 + ci], v, acc[co]);
        }
        float s5 = b5[0];
#pragma unroll
        for (int co = 0; co < 32; ++co)
            s5 = fmaf(fmaxf(acc[co], 0.f), sw5[co], s5);
        s5 = fmaxf(s5, 0.f);
        best = fmaxf(best, s5);
    }
    out[idx] = best;
}

// ---------------------------------------------------------------------------
extern "C" void kernel_launch(void* const* d_in, const int* in_sizes, int n_in,
                              void* d_out, int out_size, void* d_ws, size_t ws_size,
                              hipStream_t stream)
{
    (void)in_sizes; (void)n_in; (void)out_size; (void)ws_size;
    const float* images = (const float*)d_in[0];
    const float* tlbrs  = (const float*)d_in[1];
    const float* fw1 = (const float*)d_in[2];
    const float* fw2 = (const float*)d_in[3];
    const float* fw3 = (const float*)d_in[4];
    const float* fw4 = (const float*)d_in[5];
    const float* rw1 = (const float*)d_in[6];
    const float* rb1 = (const float*)d_in[7];
    const float* rw2 = (const float*)d_in[8];
    const float* rb2 = (const float*)d_in[9];
    const float* rw3 = (const float*)d_in[10];
    const float* rb3 = (const float*)d_in[11];
    const float* rw4 = (const float*)d_in[12];
    const float* rb4 = (const float*)d_in[13];
    const float* rw5 = (const float*)d_in[14];
    const float* rb5 = (const float*)d_in[15];
    float* wsf = (float*)d_ws;
    int* meta = (int*)d_ws;
    float* out = (float*)d_out;

    hipLaunchKernelGGL(k_meta, dim3(1), dim3(64), 0, stream, tlbrs, meta);

    // ---- backbone ----
    hipLaunchKernelGGL(k_conv, dim3(12, 12, 128), dim3(16, 16), 3 * 49 * 4, stream,
        images, fw1, (const float*)nullptr, wsf + OFF_B1,
        2, 3, 384, 384, 64, 192, 192, 7, 7, 2, 3, 3);
    hipLaunchKernelGGL(k_conv, dim3(6, 6, 512), dim3(16, 16), 64 * 9 * 4, stream,
        wsf + OFF_B1, fw2, (const float*)nullptr, wsf + OFF_B2,
        2, 64, 192, 192, 256, 96, 96, 3, 3, 2, 1, 1);
    hipLaunchKernelGGL(k_conv, dim3(3, 3, 1024), dim3(16, 16), 256 * 9 * 4, stream,
        wsf + OFF_B2, fw3, (const float*)nullptr, wsf + OFF_F3,
        2, 256, 96, 96, 512, 48, 48, 3, 3, 2, 1, 1);
    hipLaunchKernelGGL(k_conv, dim3(2, 2, 2048), dim3(16, 16), 512 * 9 * 4, stream,
        wsf + OFF_F3, fw4, (const float*)nullptr, wsf + OFF_F4,
        2, 512, 48, 48, 1024, 24, 24, 3, 3, 2, 1, 1);

    // ---- feature extraction ----
    hipLaunchKernelGGL(k_praw, dim3(1, 1024, 12), dim3(256), 0, stream,
        wsf + OFF_F3, wsf + OFF_F4, meta, wsf + OFF_PRAW);
    hipLaunchKernelGGL(k_psc, dim3(2, 1024, 36), dim3(256), 0, stream,
        wsf + OFF_PRAW, meta, wsf + OFF_PSC);
    hipLaunchKernelGGL(k_fill0, dim3((51840 + 255) / 256), dim3(256), 0, stream,
        wsf + OFF_SIMRAW, 51840);
    hipLaunchKernelGGL(k_simconv, dim3(9, 16, 36), dim3(256), 0, stream,
        wsf + OFF_F3, wsf + OFF_F4, wsf + OFF_PSC, meta, wsf + OFF_SIMRAW);
    hipLaunchKernelGGL(k_sims, dim3(324), dim3(256), 0, stream,
        wsf + OFF_SIMRAW, wsf + OFF_SIMS);

    // ---- count regressor ----
    hipLaunchKernelGGL(k_conv, dim3(3, 3, 1176), dim3(16, 16), 6 * 49 * 4, stream,
        wsf + OFF_SIMS, rw1, rb1, wsf + OFF_R1,
        6, 6, 48, 48, 196, 48, 48, 7, 7, 1, 3, 3);
    hipLaunchKernelGGL(k_up2ac, dim3((10838016 + 255) / 256), dim3(256), 0, stream,
        wsf + OFF_R1, wsf + OFF_U1, 6 * 196, 48, 48);
    hipLaunchKernelGGL(k_conv, dim3(6, 6, 768), dim3(16, 16), 196 * 25 * 4, stream,
        wsf + OFF_U1, rw2, rb2, wsf + OFF_R2,
        6, 196, 96, 96, 128, 96, 96, 5, 5, 1, 2, 2);
    hipLaunchKernelGGL(k_up2ac, dim3((28311552 + 255) / 256), dim3(256), 0, stream,
        wsf + OFF_R2, wsf + OFF_U2, 6 * 128, 96, 96);
    hipLaunchKernelGGL(k_conv, dim3(12, 12, 384), dim3(16, 16), 128 * 9 * 4, stream,
        wsf + OFF_U2, rw3, rb3, wsf + OFF_R3,
        6, 128, 192, 192, 64, 192, 192, 3, 3, 1, 1, 1);
    hipLaunchKernelGGL(k_final, dim3(1152), dim3(256), 0, stream,
        wsf + OFF_R3, rw4, rb4, rw5, rb5, out);
}

// Round 2
// 9623.888 us; speedup vs baseline: 3.7377x; 3.7377x over previous
//
#include <hip/hip_runtime.h>
#include <math.h>

// ---------------------------------------------------------------------------
// Workspace layout (float element offsets). Peak need ~196 MB.
// ---------------------------------------------------------------------------
static const size_t OFF_META   = 0;                      // 256 ints at ws start
static const size_t OFF_SIMS   = 256;                    // (6,6,48,48) = 82944
static const size_t ARENA      = 83200;
static const size_t OFF_B1     = ARENA;                  // (2,64,192,192)  = 4718592
static const size_t OFF_B2     = OFF_B1 + 4718592;       // (2,256,96,96)   = 4718592
static const size_t OFF_F3     = OFF_B2 + 4718592;       // (2,512,48,48)   = 2359296
static const size_t OFF_F4     = OFF_F3 + 2359296;       // (2,1024,24,24)  = 1179648
static const size_t OFF_PRAW   = OFF_F4 + 1179648;       // 2359296
static const size_t OFF_PSC    = OFF_PRAW + 2359296;     // 8957952
static const size_t OFF_SIMRAW = OFF_PSC + 8957952;      // 51840
// regressor phase reuses the arena (backbone/feature buffers dead by then)
static const size_t OFF_R1     = ARENA;                  // (6,196,48,48)
static const size_t OFF_U1     = OFF_R1 + 2709504;       // (6,196,96,96)
static const size_t OFF_R2     = OFF_U1 + 10838016;      // (6,128,96,96)
static const size_t OFF_U2     = OFF_R2 + 7077888;       // (6,128,192,192)
static const size_t OFF_R3     = ARENA;                  // (6,64,192,192)

// ---------------------------------------------------------------------------
__global__ __launch_bounds__(64) void k_meta(const float* __restrict__ tlbrs,
                                             int* __restrict__ meta)
{
    if (threadIdx.x != 0 || blockIdx.x != 0) return;
    const double SC[3] = {1.0, 0.9, 1.1};
    for (int b = 0; b < 2; ++b)
        for (int lvl = 0; lvl < 2; ++lvl) {
            int FH = lvl ? 24 : 48;
            float scaling = lvl ? 16.f : 8.f;
            int base = (b * 2 + lvl) * 32;
            int PH = 0, PW = 0;
            for (int p = 0; p < 3; ++p) {
                const float* t4 = tlbrs + (b * 3 + p) * 4;
                float st = t4[0] / scaling, sl = t4[1] / scaling;
                float sb = t4[2] / scaling, sr = t4[3] / scaling;
                int top  = (int)fmaxf(floorf(st), 0.f);
                int left = (int)fmaxf(floorf(sl), 0.f);
                int bot  = (int)fminf(ceilf(sb) + 1.f, (float)FH);
                int rgt  = (int)fminf(ceilf(sr) + 1.f, (float)FH);
                meta[base + p * 4 + 0] = top;
                meta[base + p * 4 + 1] = left;
                meta[base + p * 4 + 2] = bot;
                meta[base + p * 4 + 3] = rgt;
                PH = max(PH, bot - top);
                PW = max(PW, rgt - left);
            }
            meta[base + 12] = PH;
            meta[base + 13] = PW;
            for (int s = 0; s < 3; ++s) {
                int PHs = (int)ceil((double)PH * SC[s]);
                int PWs = (int)ceil((double)PW * SC[s]);
                if (PHs < 1) PHs = PH;
                if (PWs < 1) PWs = PW;
                meta[base + 14 + s * 2] = PHs;
                meta[base + 15 + s * 2] = PWs;
            }
        }
}

// ---------------------------------------------------------------------------
// Register-tiled direct conv. Block: 32x32 output tile x 8 output channels.
// Thread: 4 consecutive-x pixels x 8 couts = 32 accumulators.
// LDS: input tile for CI_B channels + weights transposed to [ci][ky][kx][co8].
// ---------------------------------------------------------------------------
template<int K, int S>
__global__ __launch_bounds__(256) void k_convT(const float* __restrict__ in,
    const float* __restrict__ w, const float* __restrict__ bias,
    float* __restrict__ out, int N, int Cin, int Hin, int Win,
    int Cout, int Hout, int Wout, int pad, int CoutG, int CI_B)
{
    constexpr int TIH = 31 * S + K;
    constexpr int TIW = 31 * S + K;
    constexpr int TILE = TIH * TIW;
    extern __shared__ float smem[];
    const int tid = threadIdx.x;
    const int cg = blockIdx.z % CoutG, n = blockIdx.z / CoutG;
    const int co0 = cg * 8;
    const int tx = tid & 7, ty = tid >> 3;
    const int ox0 = blockIdx.x * 32 + tx * 4;
    const int oy  = blockIdx.y * 32 + ty;
    const int gx0 = blockIdx.x * 32 * S - pad;
    const int gy0 = blockIdx.y * 32 * S - pad;
    const int wofs = (CI_B * TILE + 3) & ~3;

    float acc[4][8];
#pragma unroll
    for (int j = 0; j < 8; ++j) {
        float bj = (bias && co0 + j < Cout) ? bias[co0 + j] : 0.f;
#pragma unroll
        for (int px = 0; px < 4; ++px) acc[px][j] = bj;
    }

    for (int ci0 = 0; ci0 < Cin; ci0 += CI_B) {
        const int CB = min(CI_B, Cin - ci0);
        __syncthreads();
        // stage input tile
        for (int idx = tid; idx < CB * TILE; idx += 256) {
            int cc = idx / TILE, r = idx % TILE;
            int ly = r / TIW, lx = r % TIW;
            int gy = gy0 + ly, gx = gx0 + lx;
            float v = 0.f;
            if ((unsigned)gy < (unsigned)Hin && (unsigned)gx < (unsigned)Win)
                v = in[(((size_t)n * Cin + ci0 + cc) * Hin + gy) * Win + gx];
            smem[idx] = v;
        }
        // stage weights, transposed to [cc][kk][j]
        for (int idx = tid; idx < CB * K * K * 8; idx += 256) {
            int j = idx & 7, kk = (idx >> 3) % (K * K), cc = idx / (8 * K * K);
            int co = co0 + j;
            float v = 0.f;
            if (co < Cout)
                v = w[((size_t)co * Cin + ci0 + cc) * (K * K) + kk];
            smem[wofs + idx] = v;
        }
        __syncthreads();
        for (int cc = 0; cc < CB; ++cc) {
            const float* ip = smem + cc * TILE + (ty * S) * TIW + tx * 4 * S;
            const float* wp = smem + wofs + cc * K * K * 8;
#pragma unroll
            for (int ky = 0; ky < K; ++ky) {
                const float* row = ip + ky * TIW;
#pragma unroll
                for (int kx = 0; kx < K; ++kx) {
                    float w8[8];
                    *(float4*)&w8[0] = *(const float4*)(wp + (ky * K + kx) * 8);
                    *(float4*)&w8[4] = *(const float4*)(wp + (ky * K + kx) * 8 + 4);
                    float iv[4];
#pragma unroll
                    for (int px = 0; px < 4; ++px) iv[px] = row[kx + px * S];
#pragma unroll
                    for (int px = 0; px < 4; ++px)
#pragma unroll
                        for (int j = 0; j < 8; ++j)
                            acc[px][j] = fmaf(iv[px], w8[j], acc[px][j]);
                }
            }
        }
    }

    if (oy < Hout && ox0 < Wout) {
#pragma unroll
        for (int j = 0; j < 8; ++j) {
            if (co0 + j >= Cout) break;
            float4 v;
            v.x = fmaxf(acc[0][j], 0.f);
            v.y = fmaxf(acc[1][j], 0.f);
            v.z = fmaxf(acc[2][j], 0.f);
            v.w = fmaxf(acc[3][j], 0.f);
            *(float4*)&out[(((size_t)n * Cout + co0 + j) * Hout + oy) * Wout + ox0] = v;
        }
    }
}

static size_t conv_lds(int K, int S, int CI_B)
{
    int tile = (31 * S + K) * (31 * S + K);
    int wofs = (CI_B * tile + 3) & ~3;
    return (size_t)(wofs + CI_B * K * K * 8) * 4;
}

// ---------------------------------------------------------------------------
// Patch crop + half-pixel bilinear resize to (PH,PW); stride-16 planes.
// ---------------------------------------------------------------------------
__global__ __launch_bounds__(256) void k_praw(const float* __restrict__ f3,
    const float* __restrict__ f4, const int* __restrict__ meta,
    float* __restrict__ praw)
{
    int z = blockIdx.z;
    int p = z % 3, m = z / 3, lvl = m % 2, b = m / 2;
    int c = blockIdx.y;
    int FC = lvl ? 1024 : 512;
    if (c >= FC) return;
    int FH = lvl ? 24 : 48;
    const int* mb = meta + m * 32;
    int PH = mb[12], PW = mb[13];
    int oy = threadIdx.x / 16, ox = threadIdx.x % 16;
    if (oy >= PH || ox >= PW) return;
    int top = mb[p * 4 + 0], left = mb[p * 4 + 1];
    int bot = mb[p * 4 + 2], rgt = mb[p * 4 + 3];
    int h = bot - top, w = rgt - left;
    const float* fm = lvl ? (f4 + ((size_t)b * 1024 + c) * 576)
                          : (f3 + ((size_t)b * 512 + c) * 2304);
    float sy = ((oy + 0.5f) * h) / PH - 0.5f;
    sy = fminf(fmaxf(sy, 0.f), (float)(h - 1));
    int y0 = (int)floorf(sy); float ty = sy - y0; int y1 = min(y0 + 1, h - 1);
    float sx = ((ox + 0.5f) * w) / PW - 0.5f;
    sx = fminf(fmaxf(sx, 0.f), (float)(w - 1));
    int x0 = (int)floorf(sx); float tx = sx - x0; int x1 = min(x0 + 1, w - 1);
    const float* r0 = fm + (size_t)(top + y0) * FH;
    const float* r1 = fm + (size_t)(top + y1) * FH;
    float v = (1.f - ty) * ((1.f - tx) * r0[left + x0] + tx * r0[left + x1])
            +        ty  * ((1.f - tx) * r1[left + x0] + tx * r1[left + x1]);
    size_t base = (size_t)(b * 1179648 + (lvl ? 393216 : 0)) + ((size_t)p * FC + c) * 256;
    praw[base + oy * 16 + ox] = v;
}

// ---------------------------------------------------------------------------
__global__ __launch_bounds__(256) void k_psc(const float* __restrict__ praw,
    const int* __restrict__ meta, float* __restrict__ psc)
{
    int z = blockIdx.z;
    int p = z % 3, s = (z / 3) % 3, lvl = (z / 9) % 2, b = z / 18;
    int c = blockIdx.y;
    int FC = lvl ? 1024 : 512;
    if (c >= FC) return;
    const int* mb = meta + (b * 2 + lvl) * 32;
    int PH = mb[12], PW = mb[13];
    int PHs = mb[14 + s * 2], PWs = mb[15 + s * 2];
    int idx = blockIdx.x * 256 + threadIdx.x;
    int ys = idx / 18, xs = idx % 18;
    if (ys >= PHs || xs >= PWs) return;
    const float* src = praw + (size_t)(b * 1179648 + (lvl ? 393216 : 0))
                            + ((size_t)p * FC + c) * 256;
    float sy = ((ys + 0.5f) * PH) / PHs - 0.5f;
    sy = fminf(fmaxf(sy, 0.f), (float)(PH - 1));
    int y0 = (int)floorf(sy); float ty = sy - y0; int y1 = min(y0 + 1, PH - 1);
    float sx = ((xs + 0.5f) * PW) / PWs - 0.5f;
    sx = fminf(fmaxf(sx, 0.f), (float)(PW - 1));
    int x0 = (int)floorf(sx); float tx = sx - x0; int x1 = min(x0 + 1, PW - 1);
    float v = (1.f - ty) * ((1.f - tx) * src[y0 * 16 + x0] + tx * src[y0 * 16 + x1])
            +        ty  * ((1.f - tx) * src[y1 * 16 + x0] + tx * src[y1 * 16 + x1]);
    size_t base = (size_t)b * 4478976 + (lvl ? (1492992 + (size_t)s * 995328)
                                             : ((size_t)s * 497664));
    psc[base + ((size_t)p * FC + c) * 324 + ys * 18 + xs] = v;
}

__global__ __launch_bounds__(256) void k_fill0(float* p, int n)
{
    int i = blockIdx.x * 256 + threadIdx.x;
    if (i < n) p[i] = 0.f;
}

// ---------------------------------------------------------------------------
__global__ __launch_bounds__(256) void k_simconv(const float* __restrict__ f3,
    const float* __restrict__ f4, const float* __restrict__ psc,
    const int* __restrict__ meta, float* __restrict__ simraw)
{
    int z = blockIdx.z;
    int p = z % 3, s = (z / 3) % 3, lvl = (z / 9) % 2, b = z / 18;
    int FC = lvl ? 1024 : 512, FH = lvl ? 24 : 48;
    int FHFW = FH * FH;
    int cg = blockIdx.y;
    if (cg >= FC / 64) return;
    int pix = blockIdx.x * 256 + threadIdx.x;
    if (pix >= FHFW) return;
    int y = pix / FH, x = pix % FH;
    const int* mb = meta + (b * 2 + lvl) * 32;
    int PHs = mb[14 + s * 2], PWs = mb[15 + s * 2];
    int padT = PHs >> 1, padL = PWs >> 1;
    const float* fmb = lvl ? (f4 + (size_t)b * 1024 * 576)
                           : (f3 + (size_t)b * 512 * 2304);
    size_t pbase = (size_t)b * 4478976 + (lvl ? (1492992 + (size_t)s * 995328)
                                              : ((size_t)s * 497664));
    const float* wb = psc + pbase + (size_t)p * FC * 324;
    float acc = 0.f;
    for (int cc = 0; cc < 64; ++cc) {
        int c = cg * 64 + cc;
        const float* fm = fmb + (size_t)c * FHFW;
        const float* wc = wb + (size_t)c * 324;
        for (int ky = 0; ky < PHs; ++ky) {
            int iy = y - padT + ky;
            if ((unsigned)iy >= (unsigned)FH) continue;
            const float* row = fm + iy * FH;
            const float* wrow = wc + ky * 18;
            for (int kx = 0; kx < PWs; ++kx) {
                int ix = x - padL + kx;
                if ((unsigned)ix < (unsigned)FH)
                    acc = fmaf(row[ix], wrow[kx], acc);
            }
        }
    }
    size_t sb = (size_t)b * 25920 + (lvl ? (20736 + (size_t)s * 1728)
                                         : ((size_t)s * 6912));
    atomicAdd(&simraw[sb + (size_t)p * FHFW + pix], acc);
}

// ---------------------------------------------------------------------------
__global__ __launch_bounds__(256) void k_sims(const float* __restrict__ simraw,
    float* __restrict__ sims)
{
    int idx = blockIdx.x * 256 + threadIdx.x;
    if (idx >= 82944) return;
    int x = idx % 48, y = (idx / 48) % 48;
    int scat = (idx / 2304) % 6, p = (idx / 13824) % 3, b = idx / 41472;
    int lvl = scat / 3, s = scat % 3;
    float v;
    if (lvl == 0) {
        v = simraw[(size_t)b * 25920 + (size_t)s * 6912 + (size_t)p * 2304 + y * 48 + x];
    } else {
        const float* src = simraw + (size_t)b * 25920 + 20736 + (size_t)s * 1728
                                  + (size_t)p * 576;
        float sy = (y + 0.5f) * 0.5f - 0.5f; sy = fminf(fmaxf(sy, 0.f), 23.f);
        int y0 = (int)floorf(sy); float ty = sy - y0; int y1 = min(y0 + 1, 23);
        float sx = (x + 0.5f) * 0.5f - 0.5f; sx = fminf(fmaxf(sx, 0.f), 23.f);
        int x0 = (int)floorf(sx); float tx = sx - x0; int x1 = min(x0 + 1, 23);
        v = (1.f - ty) * ((1.f - tx) * src[y0 * 24 + x0] + tx * src[y0 * 24 + x1])
          +        ty  * ((1.f - tx) * src[y1 * 24 + x0] + tx * src[y1 * 24 + x1]);
    }
    sims[((size_t)(b * 3 + p) * 6 + scat) * 2304 + y * 48 + x] = v;
}

// ---------------------------------------------------------------------------
__global__ __launch_bounds__(256) void k_up2ac(const float* __restrict__ in,
    float* __restrict__ out, int NC, int Hin, int Win)
{
    int Hout = 2 * Hin, Wout = 2 * Win;
    size_t total = (size_t)NC * Hout * Wout;
    size_t idx = (size_t)blockIdx.x * 256 + threadIdx.x;
    if (idx >= total) return;
    int x = (int)(idx % Wout);
    int y = (int)((idx / Wout) % Hout);
    int nc = (int)(idx / ((size_t)Wout * Hout));
    int dh = 2 * Hin - 1, dw = 2 * Win - 1;
    int ay = y * (Hin - 1);
    int y0 = ay / dh; int y1 = min(y0 + 1, Hin - 1);
    float ty = (float)(ay - y0 * dh) / (float)dh;
    int ax = x * (Win - 1);
    int x0 = ax / dw; int x1 = min(x0 + 1, Win - 1);
    float tx = (float)(ax - x0 * dw) / (float)dw;
    const float* p = in + (size_t)nc * Hin * Win;
    float v00 = p[(size_t)y0 * Win + x0], v01 = p[(size_t)y0 * Win + x1];
    float v10 = p[(size_t)y1 * Win + x0], v11 = p[(size_t)y1 * Win + x1];
    out[idx] = (1.f - ty) * ((1.f - tx) * v00 + tx * v01)
             +        ty  * ((1.f - tx) * v10 + tx * v11);
}

// ---------------------------------------------------------------------------
__global__ __launch_bounds__(256) void k_final(const float* __restrict__ r3,
    const float* __restrict__ w4, const float* __restrict__ b4,
    const float* __restrict__ w5, const float* __restrict__ b5,
    float* __restrict__ out)
{
    __shared__ float sw4[2048];
    __shared__ float sb4[32];
    __shared__ float sw5[32];
    int tid = threadIdx.x;
    for (int i = tid; i < 2048; i += 256) sw4[i] = w4[i];
    if (tid < 32) { sb4[tid] = b4[tid]; sw5[tid] = w5[tid]; }
    __syncthreads();
    int idx = blockIdx.x * 256 + tid;
    int x = idx % 384, y = (idx / 384) % 384, b = idx / 147456;
    int ay = y * 191; int y0 = ay / 383; int y1 = min(y0 + 1, 191);
    float ty = (float)(ay - y0 * 383) / 383.f;
    int ax = x * 191; int x0 = ax / 383; int x1 = min(x0 + 1, 191);
    float tx = (float)(ax - x0 * 383) / 383.f;
    float w00 = (1.f - ty) * (1.f - tx), w01 = (1.f - ty) * tx;
    float w10 = ty * (1.f - tx), w11 = ty * tx;
    float best = 0.f;
    for (int p = 0; p < 3; ++p) {
        int n = b * 3 + p;
        float acc[32];
#pragma unroll
        for (int co = 0; co < 32; ++co) acc[co] = sb4[co];
        const float* rb = r3 + (size_t)n * 64 * 192 * 192;
        for (int ci = 0; ci < 64; ++ci) {
            const float* pl = rb + (size_t)ci * 192 * 192;
            float v = w00 * pl[y0 * 192 + x0] + w01 * pl[y0 * 192 + x1]
                    + w10 * pl[y1 * 192 + x0] + w11 * pl[y1 * 192 + x1];
#pragma unroll
            for (int co = 0; co < 32; ++co)
                acc[co] = fmaf(sw4[co * 64 + ci], v, acc[co]);
        }
        float s5 = b5[0];
#pragma unroll
        for (int co = 0; co < 32; ++co)
            s5 = fmaf(fmaxf(acc[co], 0.f), sw5[co], s5);
        s5 = fmaxf(s5, 0.f);
        best = fmaxf(best, s5);
    }
    out[idx] = best;
}

// ---------------------------------------------------------------------------
extern "C" void kernel_launch(void* const* d_in, const int* in_sizes, int n_in,
                              void* d_out, int out_size, void* d_ws, size_t ws_size,
                              hipStream_t stream)
{
    (void)in_sizes; (void)n_in; (void)out_size; (void)ws_size;
    const float* images = (const float*)d_in[0];
    const float* tlbrs  = (const float*)d_in[1];
    const float* fw1 = (const float*)d_in[2];
    const float* fw2 = (const float*)d_in[3];
    const float* fw3 = (const float*)d_in[4];
    const float* fw4 = (const float*)d_in[5];
    const float* rw1 = (const float*)d_in[6];
    const float* rb1 = (const float*)d_in[7];
    const float* rw2 = (const float*)d_in[8];
    const float* rb2 = (const float*)d_in[9];
    const float* rw3 = (const float*)d_in[10];
    const float* rb3 = (const float*)d_in[11];
    const float* rw4 = (const float*)d_in[12];
    const float* rb4 = (const float*)d_in[13];
    const float* rw5 = (const float*)d_in[14];
    const float* rb5 = (const float*)d_in[15];
    float* wsf = (float*)d_ws;
    int* meta = (int*)d_ws;
    float* out = (float*)d_out;

    hipLaunchKernelGGL(k_meta, dim3(1), dim3(64), 0, stream, tlbrs, meta);

    // ---- backbone ----
    hipLaunchKernelGGL((k_convT<7, 2>), dim3(6, 6, 16), dim3(256),
        conv_lds(7, 2, 1), stream, images, fw1, (const float*)nullptr,
        wsf + OFF_B1, 2, 3, 384, 384, 64, 192, 192, 3, 8, 1);
    hipLaunchKernelGGL((k_convT<3, 2>), dim3(3, 3, 64), dim3(256),
        conv_lds(3, 2, 2), stream, wsf + OFF_B1, fw2, (const float*)nullptr,
        wsf + OFF_B2, 2, 64, 192, 192, 256, 96, 96, 1, 32, 2);
    hipLaunchKernelGGL((k_convT<3, 2>), dim3(2, 2, 128), dim3(256),
        conv_lds(3, 2, 2), stream, wsf + OFF_B2, fw3, (const float*)nullptr,
        wsf + OFF_F3, 2, 256, 96, 96, 512, 48, 48, 1, 64, 2);
    hipLaunchKernelGGL((k_convT<3, 2>), dim3(1, 1, 256), dim3(256),
        conv_lds(3, 2, 2), stream, wsf + OFF_F3, fw4, (const float*)nullptr,
        wsf + OFF_F4, 2, 512, 48, 48, 1024, 24, 24, 1, 128, 2);

    // ---- feature extraction ----
    hipLaunchKernelGGL(k_praw, dim3(1, 1024, 12), dim3(256), 0, stream,
        wsf + OFF_F3, wsf + OFF_F4, meta, wsf + OFF_PRAW);
    hipLaunchKernelGGL(k_psc, dim3(2, 1024, 36), dim3(256), 0, stream,
        wsf + OFF_PRAW, meta, wsf + OFF_PSC);
    hipLaunchKernelGGL(k_fill0, dim3((51840 + 255) / 256), dim3(256), 0, stream,
        wsf + OFF_SIMRAW, 51840);
    hipLaunchKernelGGL(k_simconv, dim3(9, 16, 36), dim3(256), 0, stream,
        wsf + OFF_F3, wsf + OFF_F4, wsf + OFF_PSC, meta, wsf + OFF_SIMRAW);
    hipLaunchKernelGGL(k_sims, dim3(324), dim3(256), 0, stream,
        wsf + OFF_SIMRAW, wsf + OFF_SIMS);

    // ---- count regressor ----
    hipLaunchKernelGGL((k_convT<7, 1>), dim3(2, 2, 150), dim3(256),
        conv_lds(7, 1, 3), stream, wsf + OFF_SIMS, rw1, rb1,
        wsf + OFF_R1, 6, 6, 48, 48, 196, 48, 48, 3, 25, 3);
    hipLaunchKernelGGL(k_up2ac, dim3((10838016 + 255) / 256), dim3(256), 0, stream,
        wsf + OFF_R1, wsf + OFF_U1, 6 * 196, 48, 48);
    hipLaunchKernelGGL((k_convT<5, 1>), dim3(3, 3, 96), dim3(256),
        conv_lds(5, 1, 4), stream, wsf + OFF_U1, rw2, rb2,
        wsf + OFF_R2, 6, 196, 96, 96, 128, 96, 96, 2, 16, 4);
    hipLaunchKernelGGL(k_up2ac, dim3((28311552 + 255) / 256), dim3(256), 0, stream,
        wsf + OFF_R2, wsf + OFF_U2, 6 * 128, 96, 96);
    hipLaunchKernelGGL((k_convT<3, 1>), dim3(6, 6, 48), dim3(256),
        conv_lds(3, 1, 4), stream, wsf + OFF_U2, rw3, rb3,
        wsf + OFF_R3, 6, 128, 192, 192, 64, 192, 192, 1, 8, 4);
    hipLaunchKernelGGL(k_final, dim3(1152), dim3(256), 0, stream,
        wsf + OFF_R3, rw4, rb4, rw5, rb5, out);
}

// Round 4
// 3361.344 us; speedup vs baseline: 10.7015x; 2.8631x over previous
//
#include <hip/hip_runtime.h>
#include <math.h>

typedef _Float16 h8 __attribute__((ext_vector_type(8)));
typedef float f4 __attribute__((ext_vector_type(4)));

// ---------------------------------------------------------------------------
// Workspace layout (float element offsets). Peak ~197.7 MB.
// ---------------------------------------------------------------------------
static const size_t OFF_SIMS   = 256;                    // (6,6,48,48) = 82944
static const size_t ARENA      = 83200;
static const size_t OFF_B1     = ARENA;                  // (2,64,192,192)  = 4718592
static const size_t OFF_B2     = OFF_B1 + 4718592;       // (2,256,96,96)
static const size_t OFF_F3     = OFF_B2 + 4718592;       // (2,512,48,48)
static const size_t OFF_F4     = OFF_F3 + 2359296;       // (2,1024,24,24)
static const size_t OFF_PRAW   = OFF_F4 + 1179648;       // 2359296
static const size_t OFF_PSC    = OFF_PRAW + 2359296;     // 8957952
static const size_t OFF_SIMRAW = OFF_PSC + 8957952;      // 51840 -> ends 24428416
static const size_t OFF_WBB    = 24428416;               // backbone wB (f16)
// regressor phase reuses the arena
static const size_t OFF_R1     = ARENA;                  // (6,196,48,48)
static const size_t OFF_U1     = OFF_R1 + 2709504;       // (6,196,96,96)
static const size_t OFF_R2     = OFF_U1 + 10838016;      // (6,128,96,96)
static const size_t OFF_U2     = OFF_R2 + 7077888;       // (6,128,192,192) ends 49020160
static const size_t OFF_R3     = ARENA;                  // (6,64,192,192)
static const size_t OFF_WRB    = 49020160;               // regressor wB (f16)

// f16-unit offsets inside WBB / WRB
static const size_t WB1 = 0;         // 160x64    = 10240
static const size_t WB2 = 10240;     // 576x256   = 147456
static const size_t WB3 = 157696;    // 2304x512  = 1179648
static const size_t WB4 = 1337344;   // 4608x1024 = 4718592
static const size_t WR1 = 0;         // 320x256   = 81920
static const size_t WR2 = 81920;     // 4928x128  = 630784
static const size_t WR3 = 712704;    // 1152x64   = 73728

// ---------------------------------------------------------------------------
__global__ __launch_bounds__(64) void k_meta(const float* __restrict__ tlbrs,
                                             int* __restrict__ meta)
{
    if (threadIdx.x != 0 || blockIdx.x != 0) return;
    const double SC[3] = {1.0, 0.9, 1.1};
    for (int b = 0; b < 2; ++b)
        for (int lvl = 0; lvl < 2; ++lvl) {
            int FH = lvl ? 24 : 48;
            float scaling = lvl ? 16.f : 8.f;
            int base = (b * 2 + lvl) * 32;
            int PH = 0, PW = 0;
            for (int p = 0; p < 3; ++p) {
                const float* t4 = tlbrs + (b * 3 + p) * 4;
                float st = t4[0] / scaling, sl = t4[1] / scaling;
                float sb = t4[2] / scaling, sr = t4[3] / scaling;
                int top  = (int)fmaxf(floorf(st), 0.f);
                int left = (int)fmaxf(floorf(sl), 0.f);
                int bot  = (int)fminf(ceilf(sb) + 1.f, (float)FH);
                int rgt  = (int)fminf(ceilf(sr) + 1.f, (float)FH);
                meta[base + p * 4 + 0] = top;
                meta[base + p * 4 + 1] = left;
                meta[base + p * 4 + 2] = bot;
                meta[base + p * 4 + 3] = rgt;
                PH = max(PH, bot - top);
                PW = max(PW, rgt - left);
            }
            meta[base + 12] = PH;
            meta[base + 13] = PW;
            for (int s = 0; s < 3; ++s) {
                int PHs = (int)ceil((double)PH * SC[s]);
                int PWs = (int)ceil((double)PW * SC[s]);
                if (PHs < 1) PHs = PH;
                if (PWs < 1) PWs = PW;
                meta[base + 14 + s * 2] = PHs;
                meta[base + 15 + s * 2] = PWs;
            }
        }
}

// ---------------------------------------------------------------------------
// Weight pre-transform: wB[k>>3][co][k&7] = f16(w[co][k]), zero-padded.
// ---------------------------------------------------------------------------
__global__ __launch_bounds__(256) void k_wprep(const float* __restrict__ w,
    _Float16* __restrict__ wB, int Ktot, int Cout, int Coutp, int total)
{
    int idx = blockIdx.x * 256 + threadIdx.x;
    if (idx >= total) return;
    int j = idx & 7;
    int co = (idx >> 3) % Coutp;
    int kq = idx / (8 * Coutp);
    int k = kq * 8 + j;
    float v = 0.f;
    if (k < Ktot && co < Cout) v = w[(size_t)co * Ktot + k];
    wB[idx] = (_Float16)v;
}

// ---------------------------------------------------------------------------
// Implicit-GEMM conv via f16 MFMA 16x16x32, fp32 accum.
// BM=128 (pixels), BN=64 (couts), BK=32. 4 waves: wave (wr,wc) computes
// 64x32 = 4 m-tiles x 2 n-tiles. A gathered im2col (wave-uniform k), B from wB.
// asc: power-of-2 prescale applied at the f16 cast of A (avoids f16 overflow
// for large regressor activations); dsc = 1/asc re-applied in the epilogue.
// ---------------------------------------------------------------------------
template<int KK, int KW, int S>
__global__ __launch_bounds__(256) void k_convM(
    const float* __restrict__ in, const _Float16* __restrict__ wB,
    const float* __restrict__ bias, float* __restrict__ out,
    int Cin, int Hin, int Win, int Cout, int Coutp,
    int Hout, int Wout, int pad, int Kpad, float asc, float dsc)
{
    __shared__ __align__(16) _Float16 As[4][128][8];   // 8 KB
    __shared__ __align__(16) _Float16 Bs[4][64][8];    // 4 KB
    const int tid = threadIdx.x;
    const int M = Hout * Wout;
    const int n_img = blockIdx.z;
    const int m0 = blockIdx.x * 128;
    const int co0 = blockIdx.y * 64;
    const float* inb = in + (size_t)n_img * Cin * Hin * Win;

    const int wv = tid >> 6, lane = tid & 63;
    const int sq = wv;
    int mg[2] = { m0 + lane, m0 + lane + 64 };
    int ybase[2], xbase[2];
#pragma unroll
    for (int t = 0; t < 2; ++t) {
        int y = mg[t] / Wout, x = mg[t] % Wout;
        ybase[t] = y * S - pad;
        xbase[t] = x * S - pad;
    }
    const int bq = wv, bn = lane;
    const int wr = wv & 1, wc = wv >> 1;
    const int lq = lane >> 4, lr = lane & 15;

    f4 acc[4][2];
#pragma unroll
    for (int i = 0; i < 4; ++i)
#pragma unroll
        for (int j = 0; j < 2; ++j) { f4 z = {0.f, 0.f, 0.f, 0.f}; acc[i][j] = z; }

    const int Ksteps = Kpad >> 5;
    for (int kb = 0; kb < Ksteps; ++kb) {
        __syncthreads();
        // stage B: coalesced 16B copy
        {
            const _Float16* src = wB + ((size_t)(kb * 4 + bq) * Coutp + (co0 + bn)) * 8;
            *(h8*)&Bs[bq][bn][0] = *(const h8*)src;
        }
        // stage A: gather im2col, k uniform per wave
        int kBase = kb * 32 + sq * 8;
#pragma unroll
        for (int t = 0; t < 2; ++t) {
            h8 av;
            if (mg[t] < M) {
#pragma unroll
                for (int j = 0; j < 8; ++j) {
                    int k = kBase + j;
                    int ci = k / KK, r = k % KK;
                    int ky = r / KW, kx = r % KW;
                    int gy = ybase[t] + ky, gx = xbase[t] + kx;
                    float v = 0.f;
                    if (ci < Cin && (unsigned)gy < (unsigned)Hin && (unsigned)gx < (unsigned)Win)
                        v = inb[((size_t)ci * Hin + gy) * Win + gx];
                    av[j] = (_Float16)(v * asc);
                }
            } else {
#pragma unroll
                for (int j = 0; j < 8; ++j) av[j] = (_Float16)0.f;
            }
            *(h8*)&As[sq][(t << 6) + lane][0] = av;
        }
        __syncthreads();
        // compute
        h8 af[4], bf[2];
#pragma unroll
        for (int mt = 0; mt < 4; ++mt)
            af[mt] = *(const h8*)&As[lq][wr * 64 + mt * 16 + lr][0];
#pragma unroll
        for (int nt = 0; nt < 2; ++nt)
            bf[nt] = *(const h8*)&Bs[lq][wc * 32 + nt * 16 + lr][0];
#pragma unroll
        for (int mt = 0; mt < 4; ++mt)
#pragma unroll
            for (int nt = 0; nt < 2; ++nt)
                acc[mt][nt] = __builtin_amdgcn_mfma_f32_16x16x32_f16(
                    af[mt], bf[nt], acc[mt][nt], 0, 0, 0);
    }

    // epilogue: D[m = lq*4+reg][n = lr], rescale + bias + relu, float4 stores
#pragma unroll
    for (int nt = 0; nt < 2; ++nt) {
        int co = co0 + wc * 32 + nt * 16 + lr;
        if (co >= Cout) continue;
        float bv = bias ? bias[co] : 0.f;
        float* ob = out + ((size_t)n_img * Cout + co) * M;
#pragma unroll
        for (int mt = 0; mt < 4; ++mt) {
            int m = m0 + wr * 64 + mt * 16 + lq * 4;
            if (m >= M) continue;
            f4 v = acc[mt][nt];
            float4 o;
            o.x = fmaxf(fmaf(v[0], dsc, bv), 0.f);
            o.y = fmaxf(fmaf(v[1], dsc, bv), 0.f);
            o.z = fmaxf(fmaf(v[2], dsc, bv), 0.f);
            o.w = fmaxf(fmaf(v[3], dsc, bv), 0.f);
            *(float4*)&ob[m] = o;
        }
    }
}

// ---------------------------------------------------------------------------
__global__ __launch_bounds__(256) void k_praw(const float* __restrict__ f3,
    const float* __restrict__ f4_, const int* __restrict__ meta,
    float* __restrict__ praw)
{
    int z = blockIdx.z;
    int p = z % 3, m = z / 3, lvl = m % 2, b = m / 2;
    int c = blockIdx.y;
    int FC = lvl ? 1024 : 512;
    if (c >= FC) return;
    int FH = lvl ? 24 : 48;
    const int* mb = meta + m * 32;
    int PH = mb[12], PW = mb[13];
    int oy = threadIdx.x / 16, ox = threadIdx.x % 16;
    if (oy >= PH || ox >= PW) return;
    int top = mb[p * 4 + 0], left = mb[p * 4 + 1];
    int bot = mb[p * 4 + 2], rgt = mb[p * 4 + 3];
    int h = bot - top, w = rgt - left;
    const float* fm = lvl ? (f4_ + ((size_t)b * 1024 + c) * 576)
                          : (f3 + ((size_t)b * 512 + c) * 2304);
    float sy = ((oy + 0.5f) * h) / PH - 0.5f;
    sy = fminf(fmaxf(sy, 0.f), (float)(h - 1));
    int y0 = (int)floorf(sy); float ty = sy - y0; int y1 = min(y0 + 1, h - 1);
    float sx = ((ox + 0.5f) * w) / PW - 0.5f;
    sx = fminf(fmaxf(sx, 0.f), (float)(w - 1));
    int x0 = (int)floorf(sx); float tx = sx - x0; int x1 = min(x0 + 1, w - 1);
    const float* r0 = fm + (size_t)(top + y0) * FH;
    const float* r1 = fm + (size_t)(top + y1) * FH;
    float v = (1.f - ty) * ((1.f - tx) * r0[left + x0] + tx * r0[left + x1])
            +        ty  * ((1.f - tx) * r1[left + x0] + tx * r1[left + x1]);
    size_t base = (size_t)(b * 1179648 + (lvl ? 393216 : 0)) + ((size_t)p * FC + c) * 256;
    praw[base + oy * 16 + ox] = v;
}

// ---------------------------------------------------------------------------
__global__ __launch_bounds__(256) void k_psc(const float* __restrict__ praw,
    const int* __restrict__ meta, float* __restrict__ psc)
{
    int z = blockIdx.z;
    int p = z % 3, s = (z / 3) % 3, lvl = (z / 9) % 2, b = z / 18;
    int c = blockIdx.y;
    int FC = lvl ? 1024 : 512;
    if (c >= FC) return;
    const int* mb = meta + (b * 2 + lvl) * 32;
    int PH = mb[12], PW = mb[13];
    int PHs = mb[14 + s * 2], PWs = mb[15 + s * 2];
    int idx = blockIdx.x * 256 + threadIdx.x;
    int ys = idx / 18, xs = idx % 18;
    if (ys >= PHs || xs >= PWs) return;
    const float* src = praw + (size_t)(b * 1179648 + (lvl ? 393216 : 0))
                            + ((size_t)p * FC + c) * 256;
    float sy = ((ys + 0.5f) * PH) / PHs - 0.5f;
    sy = fminf(fmaxf(sy, 0.f), (float)(PH - 1));
    int y0 = (int)floorf(sy); float ty = sy - y0; int y1 = min(y0 + 1, PH - 1);
    float sx = ((xs + 0.5f) * PW) / PWs - 0.5f;
    sx = fminf(fmaxf(sx, 0.f), (float)(PW - 1));
    int x0 = (int)floorf(sx); float tx = sx - x0; int x1 = min(x0 + 1, PW - 1);
    float v = (1.f - ty) * ((1.f - tx) * src[y0 * 16 + x0] + tx * src[y0 * 16 + x1])
            +        ty  * ((1.f - tx) * src[y1 * 16 + x0] + tx * src[y1 * 16 + x1]);
    size_t base = (size_t)b * 4478976 + (lvl ? (1492992 + (size_t)s * 995328)
                                             : ((size_t)s * 497664));
    psc[base + ((size_t)p * FC + c) * 324 + ys * 18 + xs] = v;
}

__global__ __launch_bounds__(256) void k_fill0(float* p, int n)
{
    int i = blockIdx.x * 256 + threadIdx.x;
    if (i < n) p[i] = 0.f;
}

// ---------------------------------------------------------------------------
// Similarity conv, hoisted bounds + 2-channel unroll. cgroup = 32 channels.
// ---------------------------------------------------------------------------
__global__ __launch_bounds__(256) void k_simconv2(const float* __restrict__ f3,
    const float* __restrict__ f4_, const float* __restrict__ psc,
    const int* __restrict__ meta, float* __restrict__ simraw)
{
    int z = blockIdx.z;
    int p = z % 3, s = (z / 3) % 3, lvl = (z / 9) % 2, b = z / 18;
    int FC = lvl ? 1024 : 512, FH = lvl ? 24 : 48;
    int FHFW = FH * FH;
    int cg = blockIdx.y;
    if (cg >= FC / 32) return;
    int pix = blockIdx.x * 256 + threadIdx.x;
    if (pix >= FHFW) return;
    int y = pix / FH, x = pix % FH;
    const int* mb = meta + (b * 2 + lvl) * 32;
    int PHs = mb[14 + s * 2], PWs = mb[15 + s * 2];
    int padT = PHs >> 1, padL = PWs >> 1;
    int kylo = max(0, padT - y), kyhi = min(PHs, FH + padT - y);
    int kxlo = max(0, padL - x), kxhi = min(PWs, FH + padL - x);
    const float* fmb = lvl ? (f4_ + (size_t)b * 1024 * 576)
                           : (f3 + (size_t)b * 512 * 2304);
    size_t pbase = (size_t)b * 4478976 + (lvl ? (1492992 + (size_t)s * 995328)
                                              : ((size_t)s * 497664));
    const float* wb = psc + pbase + (size_t)p * FC * 324;
    float a0 = 0.f, a1 = 0.f;
    for (int cc = 0; cc < 32; cc += 2) {
        int c = cg * 32 + cc;
        const float* fm0 = fmb + (size_t)c * FHFW;
        const float* fm1 = fm0 + FHFW;
        const float* wc0 = wb + (size_t)c * 324;
        const float* wc1 = wc0 + 324;
        for (int ky = kylo; ky < kyhi; ++ky) {
            const float* r0 = fm0 + (y - padT + ky) * FH - padL;
            const float* r1 = fm1 + (y - padT + ky) * FH - padL;
            const float* w0 = wc0 + ky * 18;
            const float* w1 = wc1 + ky * 18;
            for (int kx = kxlo; kx < kxhi; ++kx) {
                a0 = fmaf(r0[x + kx], w0[kx], a0);
                a1 = fmaf(r1[x + kx], w1[kx], a1);
            }
        }
    }
    size_t sb = (size_t)b * 25920 + (lvl ? (20736 + (size_t)s * 1728)
                                         : ((size_t)s * 6912));
    atomicAdd(&simraw[sb + (size_t)p * FHFW + pix], a0 + a1);
}

// ---------------------------------------------------------------------------
__global__ __launch_bounds__(256) void k_sims(const float* __restrict__ simraw,
    float* __restrict__ sims)
{
    int idx = blockIdx.x * 256 + threadIdx.x;
    if (idx >= 82944) return;
    int x = idx % 48, y = (idx / 48) % 48;
    int scat = (idx / 2304) % 6, p = (idx / 13824) % 3, b = idx / 41472;
    int lvl = scat / 3, s = scat % 3;
    float v;
    if (lvl == 0) {
        v = simraw[(size_t)b * 25920 + (size_t)s * 6912 + (size_t)p * 2304 + y * 48 + x];
    } else {
        const float* src = simraw + (size_t)b * 25920 + 20736 + (size_t)s * 1728
                                  + (size_t)p * 576;
        float sy = (y + 0.5f) * 0.5f - 0.5f; sy = fminf(fmaxf(sy, 0.f), 23.f);
        int y0 = (int)floorf(sy); float ty = sy - y0; int y1 = min(y0 + 1, 23);
        float sx = (x + 0.5f) * 0.5f - 0.5f; sx = fminf(fmaxf(sx, 0.f), 23.f);
        int x0 = (int)floorf(sx); float tx = sx - x0; int x1 = min(x0 + 1, 23);
        v = (1.f - ty) * ((1.f - tx) * src[y0 * 24 + x0] + tx * src[y0 * 24 + x1])
          +        ty  * ((1.f - tx) * src[y1 * 24 + x0] + tx * src[y1 * 24 + x1]);
    }
    sims[((size_t)(b * 3 + p) * 6 + scat) * 2304 + y * 48 + x] = v;
}

// ---------------------------------------------------------------------------
__global__ __launch_bounds__(256) void k_up2ac(const float* __restrict__ in,
    float* __restrict__ out, int NC, int Hin, int Win)
{
    int Hout = 2 * Hin, Wout = 2 * Win;
    size_t total = (size_t)NC * Hout * Wout;
    size_t idx = (size_t)blockIdx.x * 256 + threadIdx.x;
    if (idx >= total) return;
    int x = (int)(idx % Wout);
    int y = (int)((idx / Wout) % Hout);
    int nc = (int)(idx / ((size_t)Wout * Hout));
    int dh = 2 * Hin - 1, dw = 2 * Win - 1;
    int ay = y * (Hin - 1);
    int y0 = ay / dh; int y1 = min(y0 + 1, Hin - 1);
    float ty = (float)(ay - y0 * dh) / (float)dh;
    int ax = x * (Win - 1);
    int x0 = ax / dw; int x1 = min(x0 + 1, Win - 1);
    float tx = (float)(ax - x0 * dw) / (float)dw;
    const float* p = in + (size_t)nc * Hin * Win;
    float v00 = p[(size_t)y0 * Win + x0], v01 = p[(size_t)y0 * Win + x1];
    float v10 = p[(size_t)y1 * Win + x0], v11 = p[(size_t)y1 * Win + x1];
    out[idx] = (1.f - ty) * ((1.f - tx) * v00 + tx * v01)
             +        ty  * ((1.f - tx) * v10 + tx * v11);
}

// ---------------------------------------------------------------------------
__global__ __launch_bounds__(256) void k_final(const float* __restrict__ r3,
    const float* __restrict__ w4, const float* __restrict__ b4,
    const float* __restrict__ w5, const float* __restrict__ b5,
    float* __restrict__ out)
{
    __shared__ float sw4[2048];
    __shared__ float sb4[32];
    __shared__ float sw5[32];
    int tid = threadIdx.x;
    for (int i = tid; i < 2048; i += 256) sw4[i] = w4[i];
    if (tid < 32) { sb4[tid] = b4[tid]; sw5[tid] = w5[tid]; }
    __syncthreads();
    int idx = blockIdx.x * 256 + tid;
    int x = idx % 384, y = (idx / 384) % 384, b = idx / 147456;
    int ay = y * 191; int y0 = ay / 383; int y1 = min(y0 + 1, 191);
    float ty = (float)(ay - y0 * 383) / 383.f;
    int ax = x * 191; int x0 = ax / 383; int x1 = min(x0 + 1, 191);
    float tx = (float)(ax - x0 * 383) / 383.f;
    float w00 = (1.f - ty) * (1.f - tx), w01 = (1.f - ty) * tx;
    float w10 = ty * (1.f - tx), w11 = ty * tx;
    float best = 0.f;
    for (int p = 0; p < 3; ++p) {
        int n = b * 3 + p;
        float acc[32];
#pragma unroll
        for (int co = 0; co < 32; ++co) acc[co] = sb4[co];
        const float* rb = r3 + (size_t)n * 64 * 192 * 192;
        for (int ci = 0; ci < 64; ++ci) {
            const float* pl = rb + (size_t)ci * 192 * 192;
            float v = w00 * pl[y0 * 192 + x0] + w01 * pl[y0 * 192 + x1]
                    + w10 * pl[y1 * 192 + x0] + w11 * pl[y1 * 192 + x1];
#pragma unroll
            for (int co = 0; co < 32; ++co)
                acc[co] = fmaf(sw4[co * 64 + ci], v, acc[co]);
        }
        float s5 = b5[0];
#pragma unroll
        for (int co = 0; co < 32; ++co)
            s5 = fmaf(fmaxf(acc[co], 0.f), sw5[co], s5);
        s5 = fmaxf(s5, 0.f);
        best = fmaxf(best, s5);
    }
    out[idx] = best;
}

// ---------------------------------------------------------------------------
extern "C" void kernel_launch(void* const* d_in, const int* in_sizes, int n_in,
                              void* d_out, int out_size, void* d_ws, size_t ws_size,
                              hipStream_t stream)
{
    (void)in_sizes; (void)n_in; (void)out_size; (void)ws_size;
    const float* images = (const float*)d_in[0];
    const float* tlbrs  = (const float*)d_in[1];
    const float* fw1 = (const float*)d_in[2];
    const float* fw2 = (const float*)d_in[3];
    const float* fw3 = (const float*)d_in[4];
    const float* fw4 = (const float*)d_in[5];
    const float* rw1 = (const float*)d_in[6];
    const float* rb1 = (const float*)d_in[7];
    const float* rw2 = (const float*)d_in[8];
    const float* rb2 = (const float*)d_in[9];
    const float* rw3 = (const float*)d_in[10];
    const float* rb3 = (const float*)d_in[11];
    const float* rw4 = (const float*)d_in[12];
    const float* rb4 = (const float*)d_in[13];
    const float* rw5 = (const float*)d_in[14];
    const float* rb5 = (const float*)d_in[15];
    float* wsf = (float*)d_ws;
    int* meta = (int*)d_ws;
    float* out = (float*)d_out;
    _Float16* wbb = (_Float16*)(wsf + OFF_WBB);
    _Float16* wrb = (_Float16*)(wsf + OFF_WRB);

    const float S1 = 1.f;
    const float SA = 1.f / 1024.f, SD = 1024.f;   // regressor prescale (pow2)

    hipLaunchKernelGGL(k_meta, dim3(1), dim3(64), 0, stream, tlbrs, meta);

    // ---- weight pre-transforms ----
    hipLaunchKernelGGL(k_wprep, dim3((10240 + 255) / 256), dim3(256), 0, stream,
        fw1, wbb + WB1, 147, 64, 64, 10240);
    hipLaunchKernelGGL(k_wprep, dim3((147456 + 255) / 256), dim3(256), 0, stream,
        fw2, wbb + WB2, 576, 256, 256, 147456);
    hipLaunchKernelGGL(k_wprep, dim3((1179648 + 255) / 256), dim3(256), 0, stream,
        fw3, wbb + WB3, 2304, 512, 512, 1179648);
    hipLaunchKernelGGL(k_wprep, dim3((4718592 + 255) / 256), dim3(256), 0, stream,
        fw4, wbb + WB4, 4608, 1024, 1024, 4718592);
    hipLaunchKernelGGL(k_wprep, dim3((81920 + 255) / 256), dim3(256), 0, stream,
        rw1, wrb + WR1, 294, 196, 256, 81920);
    hipLaunchKernelGGL(k_wprep, dim3((630784 + 255) / 256), dim3(256), 0, stream,
        rw2, wrb + WR2, 4900, 128, 128, 630784);
    hipLaunchKernelGGL(k_wprep, dim3((73728 + 255) / 256), dim3(256), 0, stream,
        rw3, wrb + WR3, 1152, 64, 64, 73728);

    // ---- backbone ----
    hipLaunchKernelGGL((k_convM<49, 7, 2>), dim3(288, 1, 2), dim3(256), 0, stream,
        images, wbb + WB1, (const float*)nullptr, wsf + OFF_B1,
        3, 384, 384, 64, 64, 192, 192, 3, 160, S1, S1);
    hipLaunchKernelGGL((k_convM<9, 3, 2>), dim3(72, 4, 2), dim3(256), 0, stream,
        wsf + OFF_B1, wbb + WB2, (const float*)nullptr, wsf + OFF_B2,
        64, 192, 192, 256, 256, 96, 96, 1, 576, S1, S1);
    hipLaunchKernelGGL((k_convM<9, 3, 2>), dim3(18, 8, 2), dim3(256), 0, stream,
        wsf + OFF_B2, wbb + WB3, (const float*)nullptr, wsf + OFF_F3,
        256, 96, 96, 512, 512, 48, 48, 1, 2304, S1, S1);
    hipLaunchKernelGGL((k_convM<9, 3, 2>), dim3(5, 16, 2), dim3(256), 0, stream,
        wsf + OFF_F3, wbb + WB4, (const float*)nullptr, wsf + OFF_F4,
        512, 48, 48, 1024, 1024, 24, 24, 1, 4608, S1, S1);

    // ---- feature extraction ----
    hipLaunchKernelGGL(k_praw, dim3(1, 1024, 12), dim3(256), 0, stream,
        wsf + OFF_F3, wsf + OFF_F4, meta, wsf + OFF_PRAW);
    hipLaunchKernelGGL(k_psc, dim3(2, 1024, 36), dim3(256), 0, stream,
        wsf + OFF_PRAW, meta, wsf + OFF_PSC);
    hipLaunchKernelGGL(k_fill0, dim3((51840 + 255) / 256), dim3(256), 0, stream,
        wsf + OFF_SIMRAW, 51840);
    hipLaunchKernelGGL(k_simconv2, dim3(9, 32, 36), dim3(256), 0, stream,
        wsf + OFF_F3, wsf + OFF_F4, wsf + OFF_PSC, meta, wsf + OFF_SIMRAW);
    hipLaunchKernelGGL(k_sims, dim3(324), dim3(256), 0, stream,
        wsf + OFF_SIMRAW, wsf + OFF_SIMS);

    // ---- count regressor (prescaled f16 to avoid overflow) ----
    hipLaunchKernelGGL((k_convM<49, 7, 1>), dim3(18, 4, 6), dim3(256), 0, stream,
        wsf + OFF_SIMS, wrb + WR1, rb1, wsf + OFF_R1,
        6, 48, 48, 196, 256, 48, 48, 3, 320, SA, SD);
    hipLaunchKernelGGL(k_up2ac, dim3((10838016 + 255) / 256), dim3(256), 0, stream,
        wsf + OFF_R1, wsf + OFF_U1, 6 * 196, 48, 48);
    hipLaunchKernelGGL((k_convM<25, 5, 1>), dim3(72, 2, 6), dim3(256), 0, stream,
        wsf + OFF_U1, wrb + WR2, rb2, wsf + OFF_R2,
        196, 96, 96, 128, 128, 96, 96, 2, 4928, SA, SD);
    hipLaunchKernelGGL(k_up2ac, dim3((28311552 + 255) / 256), dim3(256), 0, stream,
        wsf + OFF_R2, wsf + OFF_U2, 6 * 128, 96, 96);
    hipLaunchKernelGGL((k_convM<9, 3, 1>), dim3(288, 1, 6), dim3(256), 0, stream,
        wsf + OFF_U2, wrb + WR3, rb3, wsf + OFF_R3,
        128, 192, 192, 64, 64, 192, 192, 1, 1152, SA, SD);
    hipLaunchKernelGGL(k_final, dim3(1152), dim3(256), 0, stream,
        wsf + OFF_R3, rw4, rb4, rw5, rb5, out);
}

// Round 5
// 3226.577 us; speedup vs baseline: 11.1485x; 1.0418x over previous
//
#include <hip/hip_runtime.h>
#include <math.h>

typedef _Float16 h8 __attribute__((ext_vector_type(8)));
typedef float f4 __attribute__((ext_vector_type(4)));

// ---------------------------------------------------------------------------
// Workspace layout (float element offsets). Peak ~197.7 MB.
// ---------------------------------------------------------------------------
static const size_t OFF_SIMS   = 256;                    // (6,6,48,48) = 82944
static const size_t ARENA      = 83200;
static const size_t OFF_B1     = ARENA;                  // (2,64,192,192)
static const size_t OFF_B2     = OFF_B1 + 4718592;       // (2,256,96,96)
static const size_t OFF_F3     = OFF_B2 + 4718592;       // (2,512,48,48)
static const size_t OFF_F4     = OFF_F3 + 2359296;       // (2,1024,24,24)
static const size_t OFF_PRAW   = OFF_F4 + 1179648;       // 2359296
static const size_t OFF_PSC    = OFF_PRAW + 2359296;     // 8957952
static const size_t OFF_SIMRAW = OFF_PSC + 8957952;      // 51840 -> ends 24428416
static const size_t OFF_WBB    = 24428416;               // backbone wB (f16), ends 27456384
static const size_t OFF_WSIM   = 27456384;               // sim filter bank (f16), 7962624 fl
// regressor phase reuses the arena (WSIM dead by then; U2 overlaps it - OK)
static const size_t OFF_R1     = ARENA;                  // (6,196,48,48)
static const size_t OFF_U1     = OFF_R1 + 2709504;       // (6,196,96,96)
static const size_t OFF_R2     = OFF_U1 + 10838016;      // (6,128,96,96)
static const size_t OFF_U2     = OFF_R2 + 7077888;       // (6,128,192,192) ends 49020160
static const size_t OFF_R3     = ARENA;                  // (6,64,192,192)
static const size_t OFF_WRB    = 49020160;               // regressor wB (f16)

// f16-unit offsets inside WBB / WRB
static const size_t WB1 = 0;         // 160x64    = 10240
static const size_t WB2 = 10240;     // 576x256   = 147456
static const size_t WB3 = 157696;    // 2304x512  = 1179648
static const size_t WB4 = 1337344;   // 4608x1024 = 4718592
static const size_t WR1 = 0;         // 320x256   = 81920
static const size_t WR2 = 81920;     // 4928x128  = 630784
static const size_t WR3 = 712704;    // 1152x64   = 73728

// ---------------------------------------------------------------------------
__global__ __launch_bounds__(64) void k_meta(const float* __restrict__ tlbrs,
                                             int* __restrict__ meta)
{
    if (threadIdx.x != 0 || blockIdx.x != 0) return;
    const double SC[3] = {1.0, 0.9, 1.1};
    for (int b = 0; b < 2; ++b)
        for (int lvl = 0; lvl < 2; ++lvl) {
            int FH = lvl ? 24 : 48;
            float scaling = lvl ? 16.f : 8.f;
            int base = (b * 2 + lvl) * 32;
            int PH = 0, PW = 0;
            for (int p = 0; p < 3; ++p) {
                const float* t4 = tlbrs + (b * 3 + p) * 4;
                float st = t4[0] / scaling, sl = t4[1] / scaling;
                float sb = t4[2] / scaling, sr = t4[3] / scaling;
                int top  = (int)fmaxf(floorf(st), 0.f);
                int left = (int)fmaxf(floorf(sl), 0.f);
                int bot  = (int)fminf(ceilf(sb) + 1.f, (float)FH);
                int rgt  = (int)fminf(ceilf(sr) + 1.f, (float)FH);
                meta[base + p * 4 + 0] = top;
                meta[base + p * 4 + 1] = left;
                meta[base + p * 4 + 2] = bot;
                meta[base + p * 4 + 3] = rgt;
                PH = max(PH, bot - top);
                PW = max(PW, rgt - left);
            }
            meta[base + 12] = PH;
            meta[base + 13] = PW;
            for (int s = 0; s < 3; ++s) {
                int PHs = (int)ceil((double)PH * SC[s]);
                int PWs = (int)ceil((double)PW * SC[s]);
                if (PHs < 1) PHs = PH;
                if (PWs < 1) PWs = PW;
                meta[base + 14 + s * 2] = PHs;
                meta[base + 15 + s * 2] = PWs;
            }
        }
}

// ---------------------------------------------------------------------------
__global__ __launch_bounds__(256) void k_wprep(const float* __restrict__ w,
    _Float16* __restrict__ wB, int Ktot, int Cout, int Coutp, int total)
{
    int idx = blockIdx.x * 256 + threadIdx.x;
    if (idx >= total) return;
    int j = idx & 7;
    int co = (idx >> 3) % Coutp;
    int kq = idx / (8 * Coutp);
    int k = kq * 8 + j;
    float v = 0.f;
    if (k < Ktot && co < Cout) v = w[(size_t)co * Ktot + k];
    wB[idx] = (_Float16)v;
}

// ---------------------------------------------------------------------------
// Implicit-GEMM conv via f16 MFMA 16x16x32, fp32 accum. BM=128,BN=64,BK=32.
// ---------------------------------------------------------------------------
template<int KK, int KW, int S>
__global__ __launch_bounds__(256) void k_convM(
    const float* __restrict__ in, const _Float16* __restrict__ wB,
    const float* __restrict__ bias, float* __restrict__ out,
    int Cin, int Hin, int Win, int Cout, int Coutp,
    int Hout, int Wout, int pad, int Kpad, float asc, float dsc)
{
    __shared__ __align__(16) _Float16 As[4][128][8];   // 8 KB
    __shared__ __align__(16) _Float16 Bs[4][64][8];    // 4 KB
    const int tid = threadIdx.x;
    const int M = Hout * Wout;
    const int n_img = blockIdx.z;
    const int m0 = blockIdx.x * 128;
    const int co0 = blockIdx.y * 64;
    const float* inb = in + (size_t)n_img * Cin * Hin * Win;

    const int wv = tid >> 6, lane = tid & 63;
    const int sq = wv;
    int mg[2] = { m0 + lane, m0 + lane + 64 };
    int ybase[2], xbase[2];
#pragma unroll
    for (int t = 0; t < 2; ++t) {
        int y = mg[t] / Wout, x = mg[t] % Wout;
        ybase[t] = y * S - pad;
        xbase[t] = x * S - pad;
    }
    const int bq = wv, bn = lane;
    const int wr = wv & 1, wc = wv >> 1;
    const int lq = lane >> 4, lr = lane & 15;

    f4 acc[4][2];
#pragma unroll
    for (int i = 0; i < 4; ++i)
#pragma unroll
        for (int j = 0; j < 2; ++j) { f4 z = {0.f, 0.f, 0.f, 0.f}; acc[i][j] = z; }

    const int Ksteps = Kpad >> 5;
    for (int kb = 0; kb < Ksteps; ++kb) {
        __syncthreads();
        {
            const _Float16* src = wB + ((size_t)(kb * 4 + bq) * Coutp + (co0 + bn)) * 8;
            *(h8*)&Bs[bq][bn][0] = *(const h8*)src;
        }
        int kBase = kb * 32 + sq * 8;
#pragma unroll
        for (int t = 0; t < 2; ++t) {
            h8 av;
            if (mg[t] < M) {
#pragma unroll
                for (int j = 0; j < 8; ++j) {
                    int k = kBase + j;
                    int ci = k / KK, r = k % KK;
                    int ky = r / KW, kx = r % KW;
                    int gy = ybase[t] + ky, gx = xbase[t] + kx;
                    float v = 0.f;
                    if (ci < Cin && (unsigned)gy < (unsigned)Hin && (unsigned)gx < (unsigned)Win)
                        v = inb[((size_t)ci * Hin + gy) * Win + gx];
                    av[j] = (_Float16)(v * asc);
                }
            } else {
#pragma unroll
                for (int j = 0; j < 8; ++j) av[j] = (_Float16)0.f;
            }
            *(h8*)&As[sq][(t << 6) + lane][0] = av;
        }
        __syncthreads();
        h8 af[4], bf[2];
#pragma unroll
        for (int mt = 0; mt < 4; ++mt)
            af[mt] = *(const h8*)&As[lq][wr * 64 + mt * 16 + lr][0];
#pragma unroll
        for (int nt = 0; nt < 2; ++nt)
            bf[nt] = *(const h8*)&Bs[lq][wc * 32 + nt * 16 + lr][0];
#pragma unroll
        for (int mt = 0; mt < 4; ++mt)
#pragma unroll
            for (int nt = 0; nt < 2; ++nt)
                acc[mt][nt] = __builtin_amdgcn_mfma_f32_16x16x32_f16(
                    af[mt], bf[nt], acc[mt][nt], 0, 0, 0);
    }

#pragma unroll
    for (int nt = 0; nt < 2; ++nt) {
        int co = co0 + wc * 32 + nt * 16 + lr;
        if (co >= Cout) continue;
        float bv = bias ? bias[co] : 0.f;
        float* ob = out + ((size_t)n_img * Cout + co) * M;
#pragma unroll
        for (int mt = 0; mt < 4; ++mt) {
            int m = m0 + wr * 64 + mt * 16 + lq * 4;
            if (m >= M) continue;
            f4 v = acc[mt][nt];
            float4 o;
            o.x = fmaxf(fmaf(v[0], dsc, bv), 0.f);
            o.y = fmaxf(fmaf(v[1], dsc, bv), 0.f);
            o.z = fmaxf(fmaf(v[2], dsc, bv), 0.f);
            o.w = fmaxf(fmaf(v[3], dsc, bv), 0.f);
            *(float4*)&ob[m] = o;
        }
    }
}

// ---------------------------------------------------------------------------
__global__ __launch_bounds__(256) void k_praw(const float* __restrict__ f3,
    const float* __restrict__ f4_, const int* __restrict__ meta,
    float* __restrict__ praw)
{
    int z = blockIdx.z;
    int p = z % 3, m = z / 3, lvl = m % 2, b = m / 2;
    int c = blockIdx.y;
    int FC = lvl ? 1024 : 512;
    if (c >= FC) return;
    int FH = lvl ? 24 : 48;
    const int* mb = meta + m * 32;
    int PH = mb[12], PW = mb[13];
    int oy = threadIdx.x / 16, ox = threadIdx.x % 16;
    if (oy >= PH || ox >= PW) return;
    int top = mb[p * 4 + 0], left = mb[p * 4 + 1];
    int bot = mb[p * 4 + 2], rgt = mb[p * 4 + 3];
    int h = bot - top, w = rgt - left;
    const float* fm = lvl ? (f4_ + ((size_t)b * 1024 + c) * 576)
                          : (f3 + ((size_t)b * 512 + c) * 2304);
    float sy = ((oy + 0.5f) * h) / PH - 0.5f;
    sy = fminf(fmaxf(sy, 0.f), (float)(h - 1));
    int y0 = (int)floorf(sy); float ty = sy - y0; int y1 = min(y0 + 1, h - 1);
    float sx = ((ox + 0.5f) * w) / PW - 0.5f;
    sx = fminf(fmaxf(sx, 0.f), (float)(w - 1));
    int x0 = (int)floorf(sx); float tx = sx - x0; int x1 = min(x0 + 1, w - 1);
    const float* r0 = fm + (size_t)(top + y0) * FH;
    const float* r1 = fm + (size_t)(top + y1) * FH;
    float v = (1.f - ty) * ((1.f - tx) * r0[left + x0] + tx * r0[left + x1])
            +        ty  * ((1.f - tx) * r1[left + x0] + tx * r1[left + x1]);
    size_t base = (size_t)(b * 1179648 + (lvl ? 393216 : 0)) + ((size_t)p * FC + c) * 256;
    praw[base + oy * 16 + ox] = v;
}

// ---------------------------------------------------------------------------
__global__ __launch_bounds__(256) void k_psc(const float* __restrict__ praw,
    const int* __restrict__ meta, float* __restrict__ psc)
{
    int z = blockIdx.z;
    int p = z % 3, s = (z / 3) % 3, lvl = (z / 9) % 2, b = z / 18;
    int c = blockIdx.y;
    int FC = lvl ? 1024 : 512;
    if (c >= FC) return;
    const int* mb = meta + (b * 2 + lvl) * 32;
    int PH = mb[12], PW = mb[13];
    int PHs = mb[14 + s * 2], PWs = mb[15 + s * 2];
    int idx = blockIdx.x * 256 + threadIdx.x;
    int ys = idx / 18, xs = idx % 18;
    if (ys >= PHs || xs >= PWs) return;
    const float* src = praw + (size_t)(b * 1179648 + (lvl ? 393216 : 0))
                            + ((size_t)p * FC + c) * 256;
    float sy = ((ys + 0.5f) * PH) / PHs - 0.5f;
    sy = fminf(fmaxf(sy, 0.f), (float)(PH - 1));
    int y0 = (int)floorf(sy); float ty = sy - y0; int y1 = min(y0 + 1, PH - 1);
    float sx = ((xs + 0.5f) * PW) / PWs - 0.5f;
    sx = fminf(fmaxf(sx, 0.f), (float)(PW - 1));
    int x0 = (int)floorf(sx); float tx = sx - x0; int x1 = min(x0 + 1, PW - 1);
    float v = (1.f - ty) * ((1.f - tx) * src[y0 * 16 + x0] + tx * src[y0 * 16 + x1])
            +        ty  * ((1.f - tx) * src[y1 * 16 + x0] + tx * src[y1 * 16 + x1]);
    size_t base = (size_t)b * 4478976 + (lvl ? (1492992 + (size_t)s * 995328)
                                             : ((size_t)s * 497664));
    psc[base + ((size_t)p * FC + c) * 324 + ys * 18 + xs] = v;
}

__global__ __launch_bounds__(256) void k_fill0(float* p, int n)
{
    int i = blockIdx.x * 256 + threadIdx.x;
    if (i < n) p[i] = 0.f;
}

// ---------------------------------------------------------------------------
// Build aligned sim filter bank: W[(b,lvl)][kq][n][8] f16, k = c*324+rr*18+cc,
// n = s*3+p (9 used of 16). Filter row ky sits at rr = ky + (9 - PHs/2).
// ---------------------------------------------------------------------------
__global__ __launch_bounds__(256) void k_wsim(const float* __restrict__ psc,
    const int* __restrict__ meta, _Float16* __restrict__ W)
{
    int z = blockIdx.z;                 // b*2+lvl
    int lvl = z & 1, b = z >> 1;
    int FC = lvl ? 1024 : 512;
    int total = FC * 324 * 16;
    int e = blockIdx.x * 256 + threadIdx.x;
    if (e >= total) return;
    _Float16* Wz = W + (size_t)b * 15925248 / 2 + (lvl ? (size_t)512 * 324 * 16 : 0);
    int j = e & 7, n = (e >> 3) & 15, kq = e >> 7;
    int k = kq * 8 + j;
    int c = k / 324, r = k % 324;
    int rr = r / 18, cc = r % 18;
    float v = 0.f;
    if (n < 9) {
        int s = n / 3, p = n % 3;
        const int* mb = meta + z * 32;
        int PHs = mb[14 + s * 2], PWs = mb[15 + s * 2];
        int ky = rr - (9 - (PHs >> 1));
        int kx = cc - (9 - (PWs >> 1));
        if ((unsigned)ky < (unsigned)PHs && (unsigned)kx < (unsigned)PWs) {
            size_t base = (size_t)b * 4478976 + (lvl ? (1492992 + (size_t)s * 995328)
                                                     : ((size_t)s * 497664));
            v = psc[base + ((size_t)p * FC + c) * 324 + ky * 18 + kx];
        }
    }
    Wz[e] = (_Float16)v;
}

// ---------------------------------------------------------------------------
// Sim GEMM: per (b,lvl): out[n=(s,p)][m=pixel] = sum_k A[m][k] * W[k][n].
// A = im2col of fm with 18x18 window at pad 9. BM=128, BN=16, BK=32,
// split-K over 48 chunks, fp32 atomicAdd into simraw.
// ---------------------------------------------------------------------------
__global__ __launch_bounds__(256) void k_simM(const float* __restrict__ f3,
    const float* __restrict__ f4_, const _Float16* __restrict__ W,
    float* __restrict__ simraw)
{
    __shared__ __align__(16) _Float16 As[4][128][8];   // 8 KB
    __shared__ __align__(16) _Float16 Bs[4][16][8];    // 1 KB
    const int z = blockIdx.z;           // b*2+lvl
    const int lvl = z & 1, b = z >> 1;
    const int FC = lvl ? 1024 : 512;
    const int FH = lvl ? 24 : 48;
    const int M = FH * FH;
    const int m0 = blockIdx.x * 128;
    if (m0 >= M) return;
    const float* fm = lvl ? (f4_ + (size_t)b * 1024 * 576)
                          : (f3 + (size_t)b * 512 * 2304);
    const _Float16* Wz = W + (size_t)b * 15925248 / 2 + (lvl ? (size_t)512 * 324 * 16 : 0);
    const int KstepsTot = (FC * 324) >> 5;          // 5184 / 10368
    const int Kc = KstepsTot / 48;                  // 108 / 216
    const int kstart = blockIdx.y * Kc;

    const int tid = threadIdx.x;
    const int wv = tid >> 6, lane = tid & 63;
    const int lq = lane >> 4, lr = lane & 15;
    int mg[2] = { m0 + lane, m0 + lane + 64 };
    int ybase[2], xbase[2];
#pragma unroll
    for (int t = 0; t < 2; ++t) {
        ybase[t] = mg[t] / FH - 9;
        xbase[t] = mg[t] % FH - 9;
    }

    f4 acc[2];
    { f4 zz = {0.f, 0.f, 0.f, 0.f}; acc[0] = zz; acc[1] = zz; }

    for (int kb = 0; kb < Kc; ++kb) {
        int kq0 = (kstart + kb) * 4;
        __syncthreads();
        if (tid < 64) {
            int bq = tid >> 4, bn = tid & 15;
            *(h8*)&Bs[bq][bn][0] = *(const h8*)(Wz + ((size_t)(kq0 + bq) * 16 + bn) * 8);
        }
        int kBase = (kstart + kb) * 32 + wv * 8;
#pragma unroll
        for (int t = 0; t < 2; ++t) {
            h8 av;
            if (mg[t] < M) {
#pragma unroll
                for (int j = 0; j < 8; ++j) {
                    int k = kBase + j;
                    int c = k / 324, r = k % 324;
                    int rr = r / 18, cc = r % 18;
                    int gy = ybase[t] + rr, gx = xbase[t] + cc;
                    float v = 0.f;
                    if ((unsigned)gy < (unsigned)FH && (unsigned)gx < (unsigned)FH)
                        v = fm[(size_t)c * M + gy * FH + gx];
                    av[j] = (_Float16)v;
                }
            } else {
#pragma unroll
                for (int j = 0; j < 8; ++j) av[j] = (_Float16)0.f;
            }
            *(h8*)&As[wv][(t << 6) + lane][0] = av;
        }
        __syncthreads();
        h8 bf = *(const h8*)&Bs[lq][lr][0];
#pragma unroll
        for (int mt = 0; mt < 2; ++mt) {
            h8 af = *(const h8*)&As[lq][(wv * 2 + mt) * 16 + lr][0];
            acc[mt] = __builtin_amdgcn_mfma_f32_16x16x32_f16(af, bf, acc[mt], 0, 0, 0);
        }
    }

    // epilogue: n = lr (s,p), row = lq*4+reg within tile
    if (lr < 9) {
        int s = lr / 3, p = lr % 3;
        size_t sb = (size_t)b * 25920 + (lvl ? (20736 + (size_t)s * 1728)
                                             : ((size_t)s * 6912)) + (size_t)p * M;
#pragma unroll
        for (int mt = 0; mt < 2; ++mt) {
#pragma unroll
            for (int reg = 0; reg < 4; ++reg) {
                int m = m0 + (wv * 2 + mt) * 16 + lq * 4 + reg;
                if (m < M) atomicAdd(&simraw[sb + m], acc[mt][reg]);
            }
        }
    }
}

// ---------------------------------------------------------------------------
__global__ __launch_bounds__(256) void k_sims(const float* __restrict__ simraw,
    float* __restrict__ sims)
{
    int idx = blockIdx.x * 256 + threadIdx.x;
    if (idx >= 82944) return;
    int x = idx % 48, y = (idx / 48) % 48;
    int scat = (idx / 2304) % 6, p = (idx / 13824) % 3, b = idx / 41472;
    int lvl = scat / 3, s = scat % 3;
    float v;
    if (lvl == 0) {
        v = simraw[(size_t)b * 25920 + (size_t)s * 6912 + (size_t)p * 2304 + y * 48 + x];
    } else {
        const float* src = simraw + (size_t)b * 25920 + 20736 + (size_t)s * 1728
                                  + (size_t)p * 576;
        float sy = (y + 0.5f) * 0.5f - 0.5f; sy = fminf(fmaxf(sy, 0.f), 23.f);
        int y0 = (int)floorf(sy); float ty = sy - y0; int y1 = min(y0 + 1, 23);
        float sx = (x + 0.5f) * 0.5f - 0.5f; sx = fminf(fmaxf(sx, 0.f), 23.f);
        int x0 = (int)floorf(sx); float tx = sx - x0; int x1 = min(x0 + 1, 23);
        v = (1.f - ty) * ((1.f - tx) * src[y0 * 24 + x0] + tx * src[y0 * 24 + x1])
          +        ty  * ((1.f - tx) * src[y1 * 24 + x0] + tx * src[y1 * 24 + x1]);
    }
    sims[((size_t)(b * 3 + p) * 6 + scat) * 2304 + y * 48 + x] = v;
}

// ---------------------------------------------------------------------------
__global__ __launch_bounds__(256) void k_up2ac(const float* __restrict__ in,
    float* __restrict__ out, int NC, int Hin, int Win)
{
    int Hout = 2 * Hin, Wout = 2 * Win;
    size_t total = (size_t)NC * Hout * Wout;
    size_t idx = (size_t)blockIdx.x * 256 + threadIdx.x;
    if (idx >= total) return;
    int x = (int)(idx % Wout);
    int y = (int)((idx / Wout) % Hout);
    int nc = (int)(idx / ((size_t)Wout * Hout));
    int dh = 2 * Hin - 1, dw = 2 * Win - 1;
    int ay = y * (Hin - 1);
    int y0 = ay / dh; int y1 = min(y0 + 1, Hin - 1);
    float ty = (float)(ay - y0 * dh) / (float)dh;
    int ax = x * (Win - 1);
    int x0 = ax / dw; int x1 = min(x0 + 1, Win - 1);
    float tx = (float)(ax - x0 * dw) / (float)dw;
    const float* p = in + (size_t)nc * Hin * Win;
    float v00 = p[(size_t)y0 * Win + x0], v01 = p[(size_t)y0 * Win + x1];
    float v10 = p[(size_t)y1 * Win + x0], v11 = p[(size_t)y1 * Win + x1];
    out[idx] = (1.f - ty) * ((1.f - tx) * v00 + tx * v01)
             +        ty  * ((1.f - tx) * v10 + tx * v11);
}

// ---------------------------------------------------------------------------
__global__ __launch_bounds__(256) void k_final(const float* __restrict__ r3,
    const float* __restrict__ w4, const float* __restrict__ b4,
    const float* __restrict__ w5, const float* __restrict__ b5,
    float* __restrict__ out)
{
    __shared__ float sw4[2048];
    __shared__ float sb4[32];
    __shared__ float sw5[32];
    int tid = threadIdx.x;
    for (int i = tid; i < 2048; i += 256) sw4[i] = w4[i];
    if (tid < 32) { sb4[tid] = b4[tid]; sw5[tid] = w5[tid]; }
    __syncthreads();
    int idx = blockIdx.x * 256 + tid;
    int x = idx % 384, y = (idx / 384) % 384, b = idx / 147456;
    int ay = y * 191; int y0 = ay / 383; int y1 = min(y0 + 1, 191);
    float ty = (float)(ay - y0 * 383) / 383.f;
    int ax = x * 191; int x0 = ax / 383; int x1 = min(x0 + 1, 191);
    float tx = (float)(ax - x0 * 383) / 383.f;
    float w00 = (1.f - ty) * (1.f - tx), w01 = (1.f - ty) * tx;
    float w10 = ty * (1.f - tx), w11 = ty * tx;
    float best = 0.f;
    for (int p = 0; p < 3; ++p) {
        int n = b * 3 + p;
        float acc[32];
#pragma unroll
        for (int co = 0; co < 32; ++co) acc[co] = sb4[co];
        const float* rb = r3 + (size_t)n * 64 * 192 * 192;
        for (int ci = 0; ci < 64; ++ci) {
            const float* pl = rb + (size_t)ci * 192 * 192;
            float v = w00 * pl[y0 * 192 + x0] + w01 * pl[y0 * 192 + x1]
                    + w10 * pl[y1 * 192 + x0] + w11 * pl[y1 * 192 + x1];
#pragma unroll
            for (int co = 0; co < 32; ++co)
                acc[co] = fmaf(sw4[co * 64 + ci], v, acc[co]);
        }
        float s5 = b5[0];
#pragma unroll
        for (int co = 0; co < 32; ++co)
            s5 = fmaf(fmaxf(acc[co], 0.f), sw5[co], s5);
        s5 = fmaxf(s5, 0.f);
        best = fmaxf(best, s5);
    }
    out[idx] = best;
}

// ---------------------------------------------------------------------------
extern "C" void kernel_launch(void* const* d_in, const int* in_sizes, int n_in,
                              void* d_out, int out_size, void* d_ws, size_t ws_size,
                              hipStream_t stream)
{
    (void)in_sizes; (void)n_in; (void)out_size; (void)ws_size;
    const float* images = (const float*)d_in[0];
    const float* tlbrs  = (const float*)d_in[1];
    const float* fw1 = (const float*)d_in[2];
    const float* fw2 = (const float*)d_in[3];
    const float* fw3 = (const float*)d_in[4];
    const float* fw4 = (const float*)d_in[5];
    const float* rw1 = (const float*)d_in[6];
    const float* rb1 = (const float*)d_in[7];
    const float* rw2 = (const float*)d_in[8];
    const float* rb2 = (const float*)d_in[9];
    const float* rw3 = (const float*)d_in[10];
    const float* rb3 = (const float*)d_in[11];
    const float* rw4 = (const float*)d_in[12];
    const float* rb4 = (const float*)d_in[13];
    const float* rw5 = (const float*)d_in[14];
    const float* rb5 = (const float*)d_in[15];
    float* wsf = (float*)d_ws;
    int* meta = (int*)d_ws;
    float* out = (float*)d_out;
    _Float16* wbb = (_Float16*)(wsf + OFF_WBB);
    _Float16* wrb = (_Float16*)(wsf + OFF_WRB);
    _Float16* wsim = (_Float16*)(wsf + OFF_WSIM);

    const float S1 = 1.f;
    const float SA = 1.f / 1024.f, SD = 1024.f;   // regressor prescale (pow2)

    hipLaunchKernelGGL(k_meta, dim3(1), dim3(64), 0, stream, tlbrs, meta);

    // ---- weight pre-transforms ----
    hipLaunchKernelGGL(k_wprep, dim3((10240 + 255) / 256), dim3(256), 0, stream,
        fw1, wbb + WB1, 147, 64, 64, 10240);
    hipLaunchKernelGGL(k_wprep, dim3((147456 + 255) / 256), dim3(256), 0, stream,
        fw2, wbb + WB2, 576, 256, 256, 147456);
    hipLaunchKernelGGL(k_wprep, dim3((1179648 + 255) / 256), dim3(256), 0, stream,
        fw3, wbb + WB3, 2304, 512, 512, 1179648);
    hipLaunchKernelGGL(k_wprep, dim3((4718592 + 255) / 256), dim3(256), 0, stream,
        fw4, wbb + WB4, 4608, 1024, 1024, 4718592);
    hipLaunchKernelGGL(k_wprep, dim3((81920 + 255) / 256), dim3(256), 0, stream,
        rw1, wrb + WR1, 294, 196, 256, 81920);
    hipLaunchKernelGGL(k_wprep, dim3((630784 + 255) / 256), dim3(256), 0, stream,
        rw2, wrb + WR2, 4900, 128, 128, 630784);
    hipLaunchKernelGGL(k_wprep, dim3((73728 + 255) / 256), dim3(256), 0, stream,
        rw3, wrb + WR3, 1152, 64, 64, 73728);

    // ---- backbone ----
    hipLaunchKernelGGL((k_convM<49, 7, 2>), dim3(288, 1, 2), dim3(256), 0, stream,
        images, wbb + WB1, (const float*)nullptr, wsf + OFF_B1,
        3, 384, 384, 64, 64, 192, 192, 3, 160, S1, S1);
    hipLaunchKernelGGL((k_convM<9, 3, 2>), dim3(72, 4, 2), dim3(256), 0, stream,
        wsf + OFF_B1, wbb + WB2, (const float*)nullptr, wsf + OFF_B2,
        64, 192, 192, 256, 256, 96, 96, 1, 576, S1, S1);
    hipLaunchKernelGGL((k_convM<9, 3, 2>), dim3(18, 8, 2), dim3(256), 0, stream,
        wsf + OFF_B2, wbb + WB3, (const float*)nullptr, wsf + OFF_F3,
        256, 96, 96, 512, 512, 48, 48, 1, 2304, S1, S1);
    hipLaunchKernelGGL((k_convM<9, 3, 2>), dim3(5, 16, 2), dim3(256), 0, stream,
        wsf + OFF_F3, wbb + WB4, (const float*)nullptr, wsf + OFF_F4,
        512, 48, 48, 1024, 1024, 24, 24, 1, 4608, S1, S1);

    // ---- feature extraction ----
    hipLaunchKernelGGL(k_praw, dim3(1, 1024, 12), dim3(256), 0, stream,
        wsf + OFF_F3, wsf + OFF_F4, meta, wsf + OFF_PRAW);
    hipLaunchKernelGGL(k_psc, dim3(2, 1024, 36), dim3(256), 0, stream,
        wsf + OFF_PRAW, meta, wsf + OFF_PSC);
    hipLaunchKernelGGL(k_wsim, dim3(20736, 1, 4), dim3(256), 0, stream,
        wsf + OFF_PSC, meta, wsim);
    hipLaunchKernelGGL(k_fill0, dim3((51840 + 255) / 256), dim3(256), 0, stream,
        wsf + OFF_SIMRAW, 51840);
    hipLaunchKernelGGL(k_simM, dim3(18, 48, 4), dim3(256), 0, stream,
        wsf + OFF_F3, wsf + OFF_F4, wsim, wsf + OFF_SIMRAW);
    hipLaunchKernelGGL(k_sims, dim3(324), dim3(256), 0, stream,
        wsf + OFF_SIMRAW, wsf + OFF_SIMS);

    // ---- count regressor (prescaled f16 to avoid overflow) ----
    hipLaunchKernelGGL((k_convM<49, 7, 1>), dim3(18, 4, 6), dim3(256), 0, stream,
        wsf + OFF_SIMS, wrb + WR1, rb1, wsf + OFF_R1,
        6, 48, 48, 196, 256, 48, 48, 3, 320, SA, SD);
    hipLaunchKernelGGL(k_up2ac, dim3((10838016 + 255) / 256), dim3(256), 0, stream,
        wsf + OFF_R1, wsf + OFF_U1, 6 * 196, 48, 48);
    hipLaunchKernelGGL((k_convM<25, 5, 1>), dim3(72, 2, 6), dim3(256), 0, stream,
        wsf + OFF_U1, wrb + WR2, rb2, wsf + OFF_R2,
        196, 96, 96, 128, 128, 96, 96, 2, 4928, SA, SD);
    hipLaunchKernelGGL(k_up2ac, dim3((28311552 + 255) / 256), dim3(256), 0, stream,
        wsf + OFF_R2, wsf + OFF_U2, 6 * 128, 96, 96);
    hipLaunchKernelGGL((k_convM<9, 3, 1>), dim3(288, 1, 6), dim3(256), 0, stream,
        wsf + OFF_U2, wrb + WR3, rb3, wsf + OFF_R3,
        128, 192, 192, 64, 64, 192, 192, 1, 1152, SA, SD);
    hipLaunchKernelGGL(k_final, dim3(1152), dim3(256), 0, stream,
        wsf + OFF_R3, rw4, rb4, rw5, rb5, out);
}

// Round 7
// 1446.169 us; speedup vs baseline: 24.8737x; 2.2311x over previous
//
#include <hip/hip_runtime.h>
#include <math.h>

typedef _Float16 h8 __attribute__((ext_vector_type(8)));
typedef float f4 __attribute__((ext_vector_type(4)));

// ---------------------------------------------------------------------------
// Workspace layout (float element offsets). Peak ~141 MB.
// All activations NHWC f16 (channel-last, channels padded to mult of 8).
// Scale chain: sims stored x2^-10 (f16 range), r1 dsc=1024; regressor
// activations stored x1/64, consumers dsc=64; k_final un-scales x64. All pow2.
// ---------------------------------------------------------------------------
static const size_t OFF_SIMSH = 256;        // sims NHWC f16 (6,2304,8) = 55296 fl
static const size_t OFF_WB    = 56000;      // weight banks f16, 6895616 h = 3447808 fl
static const size_t ARENA     = 3503808;
// phase 1 (backbone + features)
static const size_t IMH    = ARENA;                 // (2,147456,8) h = 1179648 fl
static const size_t B1H    = IMH + 1179648;         // (2,36864,64) h
static const size_t B2H    = B1H + 2359296;         // (2,9216,256) h
static const size_t F3H    = B2H + 2359296;         // (2,2304,512) h = 1179648 fl
static const size_t F4H    = F3H + 1179648;         // (2,576,1024) h = 589824 fl
static const size_t PRAW   = F4H + 589824;          // fp32, 2359296
static const size_t PSC    = PRAW + 2359296;        // fp32, 8957952
static const size_t SIMRAW = PSC + 8957952;         // fp32, 51840
static const size_t WSIM   = SIMRAW + 51840;        // f16 bank, 15925248 h = 7962624 fl
// phase 2 (regressor) reuses arena
static const size_t R1H = ARENA;                    // (6,2304,200) h = 1382400 fl
static const size_t U1H = R1H + 1382400;            // (6,9216,200) h
static const size_t R2H = U1H + 5529600;            // (6,9216,128) h
static const size_t U2H = R2H + 3538944;            // (6,36864,128) h
static const size_t R3H = U2H + 14155776;           // (6,36864,64) h = 7077888 fl

// f16-unit offsets inside WB bank
static const size_t WB1 = 0;          // 52kq x 64
static const size_t WB2 = 26624;      // 72 x 256
static const size_t WB3 = 174080;     // 288 x 512
static const size_t WB4 = 1353728;    // 576 x 1024
static const size_t WR1 = 6072320;    // 52 x 256
static const size_t WR2 = 6178816;    // 628 x 128
static const size_t WR3 = 6821888;    // 144 x 64

// ---------------------------------------------------------------------------
__global__ __launch_bounds__(64) void k_meta(const float* __restrict__ tlbrs,
                                             int* __restrict__ meta)
{
    if (threadIdx.x != 0 || blockIdx.x != 0) return;
    const double SC[3] = {1.0, 0.9, 1.1};
    for (int b = 0; b < 2; ++b)
        for (int lvl = 0; lvl < 2; ++lvl) {
            int FH = lvl ? 24 : 48;
            float scaling = lvl ? 16.f : 8.f;
            int base = (b * 2 + lvl) * 32;
            int PH = 0, PW = 0;
            for (int p = 0; p < 3; ++p) {
                const float* t4 = tlbrs + (b * 3 + p) * 4;
                float st = t4[0] / scaling, sl = t4[1] / scaling;
                float sb = t4[2] / scaling, sr = t4[3] / scaling;
                int top  = (int)fmaxf(floorf(st), 0.f);
                int left = (int)fmaxf(floorf(sl), 0.f);
                int bot  = (int)fminf(ceilf(sb) + 1.f, (float)FH);
                int rgt  = (int)fminf(ceilf(sr) + 1.f, (float)FH);
                meta[base + p * 4 + 0] = top;
                meta[base + p * 4 + 1] = left;
                meta[base + p * 4 + 2] = bot;
                meta[base + p * 4 + 3] = rgt;
                PH = max(PH, bot - top);
                PW = max(PW, rgt - left);
            }
            meta[base + 12] = PH;
            meta[base + 13] = PW;
            for (int s = 0; s < 3; ++s) {
                int PHs = (int)ceil((double)PH * SC[s]);
                int PWs = (int)ceil((double)PW * SC[s]);
                if (PHs < 1) PHs = PH;
                if (PWs < 1) PWs = PW;
                meta[base + 14 + s * 2] = PHs;
                meta[base + 15 + s * 2] = PWs;
            }
        }
}

// ---------------------------------------------------------------------------
// images NCHW fp32 -> NHWC f16 (C padded to 8)
// ---------------------------------------------------------------------------
__global__ __launch_bounds__(256) void k_im2hwc(const float* __restrict__ img,
    _Float16* __restrict__ o)
{
    int idx = blockIdx.x * 256 + threadIdx.x;
    if (idx >= 2359296) return;
    int c = idx & 7;
    int pix = (idx >> 3) % 147456;
    int b = (idx >> 3) / 147456;
    float v = (c < 3) ? img[((size_t)b * 3 + c) * 147456 + pix] : 0.f;
    o[idx] = (_Float16)v;
}

// ---------------------------------------------------------------------------
// Weight bank: wB[(k/8)*Coutp*8 + co*8 + k%8], k = tap*Cinp + ci. From OIHW.
// ---------------------------------------------------------------------------
__global__ __launch_bounds__(256) void k_wprepH(const float* __restrict__ w,
    _Float16* __restrict__ wB, int Cin, int KKt, int Cinp, int Cout, int Coutp,
    int total)
{
    int idx = blockIdx.x * 256 + threadIdx.x;
    if (idx >= total) return;
    int j = idx & 7;
    int co = (idx >> 3) % Coutp;
    int kq = idx / (8 * Coutp);
    int k = kq * 8 + j;
    int tap = k / Cinp, cip = k - tap * Cinp;
    float v = 0.f;
    if (tap < KKt && cip < Cin && co < Cout)
        v = w[((size_t)co * Cin + cip) * KKt + tap];
    wB[idx] = (_Float16)v;
}

// ---------------------------------------------------------------------------
// Universal NHWC implicit-GEMM conv, f16 MFMA 16x16x32, fp32 accum.
// BM=128 px, BN=64 co, BK=32. k = tap*CINP + ci -> A-gather is ONE 16B load.
// Epilogue: val = acc*dsc + bias, relu, *osc, store f16 NHWC (co>=Cout -> 0).
// ---------------------------------------------------------------------------
template<int KK, int KW, int S, int CINP>
__global__ __launch_bounds__(256) void k_convH(
    const _Float16* __restrict__ in, const _Float16* __restrict__ wB,
    const float* __restrict__ bias, _Float16* __restrict__ out,
    int Hin, int Win, int Cout, int Coutp, int Hout, int Wout,
    int pad, int Kpad, int storeC, float dsc, float osc)
{
    __shared__ __align__(16) _Float16 As[4][128][8];
    __shared__ __align__(16) _Float16 Bs[4][64][8];
    const int tid = threadIdx.x;
    const int M = Hout * Wout;
    const int n_img = blockIdx.z;
    const int m0 = blockIdx.x * 128;
    const int co0 = blockIdx.y * 64;
    const _Float16* inb = in + (size_t)n_img * Hin * Win * CINP;

    const int wv = tid >> 6, lane = tid & 63;
    int mg[2] = { m0 + lane, m0 + lane + 64 };
    int ybase[2], xbase[2];
#pragma unroll
    for (int t = 0; t < 2; ++t) {
        int y = mg[t] / Wout, x = mg[t] % Wout;
        ybase[t] = y * S - pad;
        xbase[t] = x * S - pad;
    }
    const int wr = wv & 1, wc = wv >> 1;
    const int lq = lane >> 4, lr = lane & 15;

    f4 acc[4][2];
#pragma unroll
    for (int i = 0; i < 4; ++i)
#pragma unroll
        for (int j = 0; j < 2; ++j) { f4 z = {0.f, 0.f, 0.f, 0.f}; acc[i][j] = z; }

    const int Ksteps = Kpad >> 5;
    for (int kb = 0; kb < Ksteps; ++kb) {
        __syncthreads();
        // stage B: one 16B copy per thread
        {
            const _Float16* src = wB + ((size_t)(kb * 4 + wv) * Coutp + (co0 + lane)) * 8;
            *(h8*)&Bs[wv][lane][0] = *(const h8*)src;
        }
        // stage A: one 16B vector load per (thread, m-tile)
        int k0 = kb * 32 + wv * 8;
        int tap = k0 / CINP;
        int ci0 = k0 - tap * CINP;
        int dy = tap / KW, dx = tap - dy * KW;
#pragma unroll
        for (int t = 0; t < 2; ++t) {
            int gy = ybase[t] + dy, gx = xbase[t] + dx;
            h8 av;
            if (mg[t] < M && tap < KK &&
                (unsigned)gy < (unsigned)Hin && (unsigned)gx < (unsigned)Win) {
                av = *(const h8*)&inb[(size_t)(gy * Win + gx) * CINP + ci0];
            } else {
#pragma unroll
                for (int j = 0; j < 8; ++j) av[j] = (_Float16)0.f;
            }
            *(h8*)&As[wv][(t << 6) + lane][0] = av;
        }
        __syncthreads();
        h8 af[4], bf[2];
#pragma unroll
        for (int mt = 0; mt < 4; ++mt)
            af[mt] = *(const h8*)&As[lq][wr * 64 + mt * 16 + lr][0];
#pragma unroll
        for (int nt = 0; nt < 2; ++nt)
            bf[nt] = *(const h8*)&Bs[lq][wc * 32 + nt * 16 + lr][0];
#pragma unroll
        for (int mt = 0; mt < 4; ++mt)
#pragma unroll
            for (int nt = 0; nt < 2; ++nt)
                acc[mt][nt] = __builtin_amdgcn_mfma_f32_16x16x32_f16(
                    af[mt], bf[nt], acc[mt][nt], 0, 0, 0);
    }

    _Float16* ob = out + (size_t)n_img * M * storeC;
#pragma unroll
    for (int nt = 0; nt < 2; ++nt) {
        int co = co0 + wc * 32 + nt * 16 + lr;
        if (co >= storeC) continue;
        bool valid = co < Cout;
        float bv = (bias && valid) ? bias[co] : 0.f;
#pragma unroll
        for (int mt = 0; mt < 4; ++mt) {
#pragma unroll
            for (int reg = 0; reg < 4; ++reg) {
                int m = m0 + wr * 64 + mt * 16 + lq * 4 + reg;
                if (m < M) {
                    float v = valid
                        ? fmaxf(fmaf(acc[mt][nt][reg], dsc, bv), 0.f) * osc : 0.f;
                    ob[(size_t)m * storeC + co] = (_Float16)v;
                }
            }
        }
    }
}

// ---------------------------------------------------------------------------
// Patch crop + half-pixel bilinear (reads NHWC f16 features, writes fp32)
// ---------------------------------------------------------------------------
__global__ __launch_bounds__(256) void k_praw(const _Float16* __restrict__ f3h,
    const _Float16* __restrict__ f4h, const int* __restrict__ meta,
    float* __restrict__ praw)
{
    int z = blockIdx.z;
    int p = z % 3, m = z / 3, lvl = m % 2, b = m / 2;
    int c = blockIdx.y;
    int FC = lvl ? 1024 : 512;
    if (c >= FC) return;
    int FH = lvl ? 24 : 48;
    int fsh = lvl ? 10 : 9;
    const int* mb = meta + m * 32;
    int PH = mb[12], PW = mb[13];
    int oy = threadIdx.x / 16, ox = threadIdx.x % 16;
    if (oy >= PH || ox >= PW) return;
    int top = mb[p * 4 + 0], left = mb[p * 4 + 1];
    int bot = mb[p * 4 + 2], rgt = mb[p * 4 + 3];
    int h = bot - top, w = rgt - left;
    const _Float16* fm = lvl ? (f4h + (size_t)b * 589824)
                             : (f3h + (size_t)b * 1179648);
    float sy = ((oy + 0.5f) * h) / PH - 0.5f;
    sy = fminf(fmaxf(sy, 0.f), (float)(h - 1));
    int y0 = (int)floorf(sy); float ty = sy - y0; int y1 = min(y0 + 1, h - 1);
    float sx = ((ox + 0.5f) * w) / PW - 0.5f;
    sx = fminf(fmaxf(sx, 0.f), (float)(w - 1));
    int x0 = (int)floorf(sx); float tx = sx - x0; int x1 = min(x0 + 1, w - 1);
    float v00 = (float)fm[((size_t)((top + y0) * FH + (left + x0)) << fsh) + c];
    float v01 = (float)fm[((size_t)((top + y0) * FH + (left + x1)) << fsh) + c];
    float v10 = (float)fm[((size_t)((top + y1) * FH + (left + x0)) << fsh) + c];
    float v11 = (float)fm[((size_t)((top + y1) * FH + (left + x1)) << fsh) + c];
    float v = (1.f - ty) * ((1.f - tx) * v00 + tx * v01)
            +        ty  * ((1.f - tx) * v10 + tx * v11);
    size_t base = (size_t)(b * 1179648 + (lvl ? 393216 : 0)) + ((size_t)p * FC + c) * 256;
    praw[base + oy * 16 + ox] = v;
}

// ---------------------------------------------------------------------------
__global__ __launch_bounds__(256) void k_psc(const float* __restrict__ praw,
    const int* __restrict__ meta, float* __restrict__ psc)
{
    int z = blockIdx.z;
    int p = z % 3, s = (z / 3) % 3, lvl = (z / 9) % 2, b = z / 18;
    int c = blockIdx.y;
    int FC = lvl ? 1024 : 512;
    if (c >= FC) return;
    const int* mb = meta + (b * 2 + lvl) * 32;
    int PH = mb[12], PW = mb[13];
    int PHs = mb[14 + s * 2], PWs = mb[15 + s * 2];
    int idx = blockIdx.x * 256 + threadIdx.x;
    int ys = idx / 18, xs = idx % 18;
    if (ys >= PHs || xs >= PWs) return;
    const float* src = praw + (size_t)(b * 1179648 + (lvl ? 393216 : 0))
                            + ((size_t)p * FC + c) * 256;
    float sy = ((ys + 0.5f) * PH) / PHs - 0.5f;
    sy = fminf(fmaxf(sy, 0.f), (float)(PH - 1));
    int y0 = (int)floorf(sy); float ty = sy - y0; int y1 = min(y0 + 1, PH - 1);
    float sx = ((xs + 0.5f) * PW) / PWs - 0.5f;
    sx = fminf(fmaxf(sx, 0.f), (float)(PW - 1));
    int x0 = (int)floorf(sx); float tx = sx - x0; int x1 = min(x0 + 1, PW - 1);
    float v = (1.f - ty) * ((1.f - tx) * src[y0 * 16 + x0] + tx * src[y0 * 16 + x1])
            +        ty  * ((1.f - tx) * src[y1 * 16 + x0] + tx * src[y1 * 16 + x1]);
    size_t base = (size_t)b * 4478976 + (lvl ? (1492992 + (size_t)s * 995328)
                                             : ((size_t)s * 497664));
    psc[base + ((size_t)p * FC + c) * 324 + ys * 18 + xs] = v;
}

__global__ __launch_bounds__(256) void k_fill0(float* p, int n)
{
    int i = blockIdx.x * 256 + threadIdx.x;
    if (i < n) p[i] = 0.f;
}

// ---------------------------------------------------------------------------
// Sim filter bank, k = tap*FC + c ordering: Wz[kq][n(16)][8] f16.
// ---------------------------------------------------------------------------
__global__ __launch_bounds__(256) void k_wsim(const float* __restrict__ psc,
    const int* __restrict__ meta, _Float16* __restrict__ W)
{
    int z = blockIdx.z;                 // b*2+lvl
    int lvl = z & 1, b = z >> 1;
    int FC = lvl ? 1024 : 512;
    int fsh = lvl ? 10 : 9;
    int total = FC * 324 * 16;
    int e = blockIdx.x * 256 + threadIdx.x;
    if (e >= total) return;
    _Float16* Wz = W + (size_t)b * 7962624 + (lvl ? 2654208 : 0);
    int j = e & 7, n = (e >> 3) & 15, kq = e >> 7;
    int k = kq * 8 + j;
    int tap = k >> fsh, c = k & (FC - 1);
    int rr = tap / 18, cc = tap - rr * 18;
    float v = 0.f;
    if (n < 9) {
        int s = n / 3, p = n % 3;
        const int* mb = meta + z * 32;
        int PHs = mb[14 + s * 2], PWs = mb[15 + s * 2];
        int ky = rr - (9 - (PHs >> 1));
        int kx = cc - (9 - (PWs >> 1));
        if ((unsigned)ky < (unsigned)PHs && (unsigned)kx < (unsigned)PWs) {
            size_t base = (size_t)b * 4478976 + (lvl ? (1492992 + (size_t)s * 995328)
                                                     : ((size_t)s * 497664));
            v = psc[base + ((size_t)p * FC + c) * 324 + ky * 18 + kx];
        }
    }
    Wz[e] = (_Float16)v;
}

// ---------------------------------------------------------------------------
// Sim GEMM, NHWC gather: k = tap*FC + c. BM=128, BN=16, BK=32, split-K 48.
// ---------------------------------------------------------------------------
__global__ __launch_bounds__(256) void k_simM(const _Float16* __restrict__ f3h,
    const _Float16* __restrict__ f4h, const _Float16* __restrict__ W,
    float* __restrict__ simraw)
{
    __shared__ __align__(16) _Float16 As[4][128][8];
    __shared__ __align__(16) _Float16 Bs[4][16][8];
    const int z = blockIdx.z;           // b*2+lvl
    const int lvl = z & 1, b = z >> 1;
    const int FC = lvl ? 1024 : 512;
    const int fsh = lvl ? 10 : 9;
    const int FH = lvl ? 24 : 48;
    const int M = FH * FH;
    const int m0 = blockIdx.x * 128;
    if (m0 >= M) return;
    const _Float16* fm = lvl ? (f4h + (size_t)b * 589824)
                             : (f3h + (size_t)b * 1179648);
    const _Float16* Wz = W + (size_t)b * 7962624 + (lvl ? 2654208 : 0);
    const int KstepsTot = (FC * 324) >> 5;
    const int Kc = KstepsTot / 48;
    const int kstart = blockIdx.y * Kc;

    const int tid = threadIdx.x;
    const int wv = tid >> 6, lane = tid & 63;
    const int lq = lane >> 4, lr = lane & 15;
    int mg[2] = { m0 + lane, m0 + lane + 64 };
    int yb[2], xb[2];
#pragma unroll
    for (int t = 0; t < 2; ++t) {
        yb[t] = mg[t] / FH - 9;
        xb[t] = mg[t] % FH - 9;
    }

    f4 acc[2];
    { f4 zz = {0.f, 0.f, 0.f, 0.f}; acc[0] = zz; acc[1] = zz; }

    for (int kb = 0; kb < Kc; ++kb) {
        int ks = kstart + kb;
        __syncthreads();
        if (tid < 64) {
            int bq = tid >> 4, bn = tid & 15;
            *(h8*)&Bs[bq][bn][0] = *(const h8*)(Wz + ((size_t)(ks * 4 + bq) * 16 + bn) * 8);
        }
        int k0 = ks * 32 + wv * 8;
        int tap = k0 >> fsh;
        int c0 = k0 & (FC - 1);
        int dy = tap / 18, dx = tap - dy * 18;
#pragma unroll
        for (int t = 0; t < 2; ++t) {
            int gy = yb[t] + dy, gx = xb[t] + dx;
            h8 av;
            if (mg[t] < M && (unsigned)gy < (unsigned)FH && (unsigned)gx < (unsigned)FH) {
                av = *(const h8*)&fm[((size_t)(gy * FH + gx) << fsh) + c0];
            } else {
#pragma unroll
                for (int j = 0; j < 8; ++j) av[j] = (_Float16)0.f;
            }
            *(h8*)&As[wv][(t << 6) + lane][0] = av;
        }
        __syncthreads();
        h8 bf = *(const h8*)&Bs[lq][lr][0];
#pragma unroll
        for (int mt = 0; mt < 2; ++mt) {
            h8 af = *(const h8*)&As[lq][(wv * 2 + mt) * 16 + lr][0];
            acc[mt] = __builtin_amdgcn_mfma_f32_16x16x32_f16(af, bf, acc[mt], 0, 0, 0);
        }
    }

    if (lr < 9) {
        int s = lr / 3, p = lr % 3;
        size_t sb = (size_t)b * 25920 + (lvl ? (20736 + (size_t)s * 1728)
                                             : ((size_t)s * 6912)) + (size_t)p * M;
#pragma unroll
        for (int mt = 0; mt < 2; ++mt) {
#pragma unroll
            for (int reg = 0; reg < 4; ++reg) {
                int m = m0 + (wv * 2 + mt) * 16 + lq * 4 + reg;
                if (m < M) atomicAdd(&simraw[sb + m], acc[mt][reg]);
            }
        }
    }
}

// ---------------------------------------------------------------------------
// Assemble sims -> NHWC f16 (8 ch: 6 used + 2 zero), stored x 2^-10 for
// f16 range safety (f4-level sims can exceed 65504). r1 conv dsc=1024.
// ---------------------------------------------------------------------------
__global__ __launch_bounds__(256) void k_sims(const float* __restrict__ simraw,
    _Float16* __restrict__ simsh)
{
    int idx = blockIdx.x * 256 + threadIdx.x;
    if (idx >= 110592) return;
    int scat = idx & 7;
    int rest = idx >> 3;                 // ((b*3+p)*2304 + y*48+x)
    int x = rest % 48, y = (rest / 48) % 48;
    int p = (rest / 2304) % 3, b = rest / 6912;
    float v = 0.f;
    if (scat < 6) {
        int lvl = scat / 3, s = scat % 3;
        if (lvl == 0) {
            v = simraw[(size_t)b * 25920 + (size_t)s * 6912 + (size_t)p * 2304 + y * 48 + x];
        } else {
            const float* src = simraw + (size_t)b * 25920 + 20736 + (size_t)s * 1728
                                      + (size_t)p * 576;
            float sy = (y + 0.5f) * 0.5f - 0.5f; sy = fminf(fmaxf(sy, 0.f), 23.f);
            int y0 = (int)floorf(sy); float ty = sy - y0; int y1 = min(y0 + 1, 23);
            float sx = (x + 0.5f) * 0.5f - 0.5f; sx = fminf(fmaxf(sx, 0.f), 23.f);
            int x0 = (int)floorf(sx); float tx = sx - x0; int x1 = min(x0 + 1, 23);
            v = (1.f - ty) * ((1.f - tx) * src[y0 * 24 + x0] + tx * src[y0 * 24 + x1])
              +        ty  * ((1.f - tx) * src[y1 * 24 + x0] + tx * src[y1 * 24 + x1]);
        }
    }
    simsh[idx] = (_Float16)(v * 0.0009765625f);   // x 2^-10
}

// ---------------------------------------------------------------------------
// align-corners 2x bilinear upsample, NHWC f16, 8 channels per thread
// ---------------------------------------------------------------------------
__global__ __launch_bounds__(256) void k_up2acH(const h8* __restrict__ in,
    h8* __restrict__ out, int N_, int Hin, int Win, int Cg)
{
    int Hout = 2 * Hin, Wout = 2 * Win;
    size_t total = (size_t)N_ * Hout * Wout * Cg;
    size_t idx = (size_t)blockIdx.x * 256 + threadIdx.x;
    if (idx >= total) return;
    int cg = (int)(idx % Cg);
    size_t r = idx / Cg;
    int x = (int)(r % Wout);
    int y = (int)((r / Wout) % Hout);
    int n = (int)(r / ((size_t)Wout * Hout));
    int dh = 2 * Hin - 1, dw = 2 * Win - 1;
    int ay = y * (Hin - 1);
    int y0 = ay / dh; int y1 = min(y0 + 1, Hin - 1);
    float ty = (float)(ay - y0 * dh) / (float)dh;
    int ax = x * (Win - 1);
    int x0 = ax / dw; int x1 = min(x0 + 1, Win - 1);
    float tx = (float)(ax - x0 * dw) / (float)dw;
    const h8* base = in + (size_t)n * Hin * Win * Cg;
    h8 a = base[((size_t)y0 * Win + x0) * Cg + cg];
    h8 b8 = base[((size_t)y0 * Win + x1) * Cg + cg];
    h8 c8 = base[((size_t)y1 * Win + x0) * Cg + cg];
    h8 d8 = base[((size_t)y1 * Win + x1) * Cg + cg];
    float w00 = (1.f - ty) * (1.f - tx), w01 = (1.f - ty) * tx;
    float w10 = ty * (1.f - tx), w11 = ty * tx;
    h8 o;
#pragma unroll
    for (int j = 0; j < 8; ++j)
        o[j] = (_Float16)(w00 * (float)a[j] + w01 * (float)b8[j]
                        + w10 * (float)c8[j] + w11 * (float)d8[j]);
    out[idx] = o;
}

// ---------------------------------------------------------------------------
// Fused: up2x_ac(r3, NHWC f16, x64 unscale) -> 1x1 -> 1x1 -> max over p
// ---------------------------------------------------------------------------
__global__ __launch_bounds__(256) void k_final(const h8* __restrict__ r3h,
    const float* __restrict__ w4, const float* __restrict__ b4,
    const float* __restrict__ w5, const float* __restrict__ b5,
    float* __restrict__ out)
{
    __shared__ float sw4[2048];
    __shared__ float sb4[32];
    __shared__ float sw5[32];
    int tid = threadIdx.x;
    for (int i = tid; i < 2048; i += 256) sw4[i] = w4[i];
    if (tid < 32) { sb4[tid] = b4[tid]; sw5[tid] = w5[tid]; }
    __syncthreads();
    int idx = blockIdx.x * 256 + tid;
    int x = idx % 384, y = (idx / 384) % 384, b = idx / 147456;
    int ay = y * 191; int y0 = ay / 383; int y1 = min(y0 + 1, 191);
    float ty = (float)(ay - y0 * 383) / 383.f;
    int ax = x * 191; int x0 = ax / 383; int x1 = min(x0 + 1, 191);
    float tx = (float)(ax - x0 * 383) / 383.f;
    float w00 = (1.f - ty) * (1.f - tx), w01 = (1.f - ty) * tx;
    float w10 = ty * (1.f - tx), w11 = ty * tx;
    float best = 0.f;
    for (int p = 0; p < 3; ++p) {
        int n = b * 3 + p;
        float acc[32];
#pragma unroll
        for (int co = 0; co < 32; ++co) acc[co] = sb4[co];
        const h8* rb = r3h + (size_t)n * 36864 * 8;
        for (int cg = 0; cg < 8; ++cg) {
            h8 a00 = rb[(size_t)(y0 * 192 + x0) * 8 + cg];
            h8 a01 = rb[(size_t)(y0 * 192 + x1) * 8 + cg];
            h8 a10 = rb[(size_t)(y1 * 192 + x0) * 8 + cg];
            h8 a11 = rb[(size_t)(y1 * 192 + x1) * 8 + cg];
#pragma unroll
            for (int jj = 0; jj < 8; ++jj) {
                float v = (w00 * (float)a00[jj] + w01 * (float)a01[jj]
                         + w10 * (float)a10[jj] + w11 * (float)a11[jj]) * 64.f;
                int ci = cg * 8 + jj;
#pragma unroll
                for (int co = 0; co < 32; ++co)
                    acc[co] = fmaf(sw4[co * 64 + ci], v, acc[co]);
            }
        }
        float s5 = b5[0];
#pragma unroll
        for (int co = 0; co < 32; ++co)
            s5 = fmaf(fmaxf(acc[co], 0.f), sw5[co], s5);
        s5 = fmaxf(s5, 0.f);
        best = fmaxf(best, s5);
    }
    out[idx] = best;
}

// ---------------------------------------------------------------------------
extern "C" void kernel_launch(void* const* d_in, const int* in_sizes, int n_in,
                              void* d_out, int out_size, void* d_ws, size_t ws_size,
                              hipStream_t stream)
{
    (void)in_sizes; (void)n_in; (void)out_size; (void)ws_size;
    const float* images = (const float*)d_in[0];
    const float* tlbrs  = (const float*)d_in[1];
    const float* fw1 = (const float*)d_in[2];
    const float* fw2 = (const float*)d_in[3];
    const float* fw3 = (const float*)d_in[4];
    const float* fw4 = (const float*)d_in[5];
    const float* rw1 = (const float*)d_in[6];
    const float* rb1 = (const float*)d_in[7];
    const float* rw2 = (const float*)d_in[8];
    const float* rb2 = (const float*)d_in[9];
    const float* rw3 = (const float*)d_in[10];
    const float* rb3 = (const float*)d_in[11];
    const float* rw4 = (const float*)d_in[12];
    const float* rb4 = (const float*)d_in[13];
    const float* rw5 = (const float*)d_in[14];
    const float* rb5 = (const float*)d_in[15];
    float* wsf = (float*)d_ws;
    int* meta = (int*)d_ws;
    float* out = (float*)d_out;
    _Float16* wb    = (_Float16*)(wsf + OFF_WB);
    _Float16* simsh = (_Float16*)(wsf + OFF_SIMSH);
    _Float16* imh   = (_Float16*)(wsf + IMH);
    _Float16* b1h   = (_Float16*)(wsf + B1H);
    _Float16* b2h   = (_Float16*)(wsf + B2H);
    _Float16* f3h   = (_Float16*)(wsf + F3H);
    _Float16* f4h   = (_Float16*)(wsf + F4H);
    _Float16* wsim  = (_Float16*)(wsf + WSIM);
    _Float16* r1h   = (_Float16*)(wsf + R1H);
    _Float16* u1h   = (_Float16*)(wsf + U1H);
    _Float16* r2h   = (_Float16*)(wsf + R2H);
    _Float16* u2h   = (_Float16*)(wsf + U2H);
    _Float16* r3h   = (_Float16*)(wsf + R3H);

    const float INV64 = 1.f / 64.f;

    hipLaunchKernelGGL(k_meta, dim3(1), dim3(64), 0, stream, tlbrs, meta);
    hipLaunchKernelGGL(k_im2hwc, dim3(9216), dim3(256), 0, stream, images, imh);

    // ---- weight banks ----
    hipLaunchKernelGGL(k_wprepH, dim3(104), dim3(256), 0, stream,
        fw1, wb + WB1, 3, 49, 8, 64, 64, 26624);
    hipLaunchKernelGGL(k_wprepH, dim3(576), dim3(256), 0, stream,
        fw2, wb + WB2, 64, 9, 64, 256, 256, 147456);
    hipLaunchKernelGGL(k_wprepH, dim3(4608), dim3(256), 0, stream,
        fw3, wb + WB3, 256, 9, 256, 512, 512, 1179648);
    hipLaunchKernelGGL(k_wprepH, dim3(18432), dim3(256), 0, stream,
        fw4, wb + WB4, 512, 9, 512, 1024, 1024, 4718592);
    hipLaunchKernelGGL(k_wprepH, dim3(416), dim3(256), 0, stream,
        rw1, wb + WR1, 6, 49, 8, 196, 256, 106496);
    hipLaunchKernelGGL(k_wprepH, dim3(2512), dim3(256), 0, stream,
        rw2, wb + WR2, 196, 25, 200, 128, 128, 643072);
    hipLaunchKernelGGL(k_wprepH, dim3(288), dim3(256), 0, stream,
        rw3, wb + WR3, 128, 9, 128, 64, 64, 73728);

    // ---- backbone (NHWC f16) ----
    hipLaunchKernelGGL((k_convH<49, 7, 2, 8>), dim3(288, 1, 2), dim3(256), 0, stream,
        imh, wb + WB1, (const float*)nullptr, b1h,
        384, 384, 64, 64, 192, 192, 3, 416, 64, 1.f, 1.f);
    hipLaunchKernelGGL((k_convH<9, 3, 2, 64>), dim3(72, 4, 2), dim3(256), 0, stream,
        b1h, wb + WB2, (const float*)nullptr, b2h,
        192, 192, 256, 256, 96, 96, 1, 576, 256, 1.f, 1.f);
    hipLaunchKernelGGL((k_convH<9, 3, 2, 256>), dim3(18, 8, 2), dim3(256), 0, stream,
        b2h, wb + WB3, (const float*)nullptr, f3h,
        96, 96, 512, 512, 48, 48, 1, 2304, 512, 1.f, 1.f);
    hipLaunchKernelGGL((k_convH<9, 3, 2, 512>), dim3(5, 16, 2), dim3(256), 0, stream,
        f3h, wb + WB4, (const float*)nullptr, f4h,
        48, 48, 1024, 1024, 24, 24, 1, 4608, 1024, 1.f, 1.f);

    // ---- feature extraction ----
    hipLaunchKernelGGL(k_praw, dim3(1, 1024, 12), dim3(256), 0, stream,
        f3h, f4h, meta, wsf + PRAW);
    hipLaunchKernelGGL(k_psc, dim3(2, 1024, 36), dim3(256), 0, stream,
        wsf + PRAW, meta, wsf + PSC);
    hipLaunchKernelGGL(k_wsim, dim3(20736, 1, 4), dim3(256), 0, stream,
        wsf + PSC, meta, wsim);
    hipLaunchKernelGGL(k_fill0, dim3(203), dim3(256), 0, stream,
        wsf + SIMRAW, 51840);
    hipLaunchKernelGGL(k_simM, dim3(18, 48, 4), dim3(256), 0, stream,
        f3h, f4h, wsim, wsf + SIMRAW);
    hipLaunchKernelGGL(k_sims, dim3(432), dim3(256), 0, stream,
        wsf + SIMRAW, simsh);

    // ---- count regressor (NHWC f16; sims scaled 2^-10 -> r1 dsc=1024) ----
    hipLaunchKernelGGL((k_convH<49, 7, 1, 8>), dim3(18, 4, 6), dim3(256), 0, stream,
        simsh, wb + WR1, rb1, r1h,
        48, 48, 196, 256, 48, 48, 3, 416, 200, 1024.f, INV64);
    hipLaunchKernelGGL(k_up2acH, dim3(5400), dim3(256), 0, stream,
        (const h8*)r1h, (h8*)u1h, 6, 48, 48, 25);
    hipLaunchKernelGGL((k_convH<25, 5, 1, 200>), dim3(72, 2, 6), dim3(256), 0, stream,
        u1h, wb + WR2, rb2, r2h,
        96, 96, 128, 128, 96, 96, 2, 5024, 128, 64.f, INV64);
    hipLaunchKernelGGL(k_up2acH, dim3(13824), dim3(256), 0, stream,
        (const h8*)r2h, (h8*)u2h, 6, 96, 96, 16);
    hipLaunchKernelGGL((k_convH<9, 3, 1, 128>), dim3(288, 1, 6), dim3(256), 0, stream,
        u2h, wb + WR3, rb3, r3h,
        192, 192, 64, 64, 192, 192, 1, 1152, 64, 64.f, INV64);
    hipLaunchKernelGGL(k_final, dim3(1152), dim3(256), 0, stream,
        (const h8*)r3h, rw4, rb4, rw5, rb5, out);
}